// Round 1
// baseline (1584.413 us; speedup 1.0000x reference)
//
#include <hip/hip_runtime.h>
#include <stdint.h>

#define NN 50000
#define EE 800000
#define FIN 256
#define HD 128
#define DD 32
#define KK 25000
#define SLOPEF 0.4f
#define NEGF (-1e9f)
#define ATT_OFF 34
#define STR_OFF (34 + EE * 4)

// ---------- helpers ----------
__device__ __forceinline__ unsigned fkey(float x) {
    unsigned u = __float_as_uint(x);
    return (u & 0x80000000u) ? ~u : (u | 0x80000000u);   // monotone float->uint
}
__device__ __forceinline__ float unfkey(unsigned k) {
    unsigned u = (k & 0x80000000u) ? (k ^ 0x80000000u) : ~k;
    return __uint_as_float(u);
}
__device__ __forceinline__ float lrelu(float v) { return v > 0.f ? v : SLOPEF * v; }

// ---------- pointer bundle ----------
struct P {
    // inputs
    const float *feature, *strength, *W0, *b0, *al0, *ar0, *Wc0, *bc0;
    const float *W1, *b1, *al1, *ar1, *gW, *gb, *cW, *cb;
    const int *src, *dst;
    // zeroed scratch
    double *s0, *s1, *Zacc, *racc;
    int *deg_i, *deg_o, *cur0, *deg1, *cur1, *cnt;
    unsigned *bins, *gmaxk, *rs;      // rs[0]=prefix/pivot, rs[1]=remaining/needTies
    // other scratch
    unsigned *m0k, *m1k, *keys;
    int *csr_eid, *csr_src, *off0, *off1, *sel, *slot, *list;
    float *z0, *x, *alpha0, *el0, *er0, *hc, *score, *xk, *z1;
    float *el1, *er1, *out1, *res, *g, *tscale;
    float *out;                        // d_out (float32)
};

// ---------- init m-keys ----------
__global__ void k_init(P p) {
    int i = blockIdx.x * blockDim.x + threadIdx.x;
    unsigned v = fkey(NEGF);
    if (i < NN * 4) p.m0k[i] = v;
    if (i < KK * 4) p.m1k[i] = v;
}

// ---------- fp32 tiled GEMM: C[M,Nd] = A[M,Kd] @ B[Kd,Nd] ----------
#define BM 64
#define BN 64
#define BK 16
__global__ __launch_bounds__(256) void k_gemm(const float* __restrict__ A,
                                              const float* __restrict__ B,
                                              float* __restrict__ C,
                                              int M, int Nd, int Kd) {
    __shared__ float As[BK][BM + 1];
    __shared__ float Bs[BK][BN];
    int bm = blockIdx.y * BM, bn = blockIdx.x * BN;
    int tid = threadIdx.x;
    int tr = tid >> 4, tc = tid & 15;  // 16x16 threads, each 4x4
    float acc[4][4] = {};
    for (int k0 = 0; k0 < Kd; k0 += BK) {
        {   // A tile: 64 rows x 16 k
            int row = tid >> 2, col = (tid & 3) << 2;
            int gr = bm + row;
            float4 v = {0.f, 0.f, 0.f, 0.f};
            if (gr < M) v = *(const float4*)(A + (size_t)gr * Kd + k0 + col);
            As[col + 0][row] = v.x; As[col + 1][row] = v.y;
            As[col + 2][row] = v.z; As[col + 3][row] = v.w;
        }
        {   // B tile: 16 k x 64 cols
            int kr = tid >> 4, col = (tid & 15) << 2;
            float4 v = *(const float4*)(B + (size_t)(k0 + kr) * Nd + bn + col);
            *(float4*)&Bs[kr][col] = v;
        }
        __syncthreads();
#pragma unroll
        for (int kk = 0; kk < BK; kk++) {
            float a[4], b[4];
#pragma unroll
            for (int i = 0; i < 4; i++) a[i] = As[kk][tr * 4 + i];
#pragma unroll
            for (int j = 0; j < 4; j++) b[j] = Bs[kk][tc * 4 + j];
#pragma unroll
            for (int i = 0; i < 4; i++)
#pragma unroll
                for (int j = 0; j < 4; j++) acc[i][j] += a[i] * b[j];
        }
        __syncthreads();
    }
#pragma unroll
    for (int i = 0; i < 4; i++) {
        int gr = bm + tr * 4 + i;
        if (gr < M) {
            float4 v = {acc[i][0], acc[i][1], acc[i][2], acc[i][3]};
            *(float4*)(C + (size_t)gr * Nd + bn + tc * 4) = v;
        }
    }
}

// ---------- per-(node,head) attn logits el/er ----------
__global__ void k_elr(const float* __restrict__ z, const float* __restrict__ al,
                      const float* __restrict__ ar, float* __restrict__ el,
                      float* __restrict__ er, int n) {
    int i = blockIdx.x * blockDim.x + threadIdx.x;
    if (i >= n * 4) return;
    int v = i >> 2, h = i & 3;
    const float* zr = z + (size_t)v * HD + h * DD;
    const float* a = al + h * DD;
    const float* b = ar + h * DD;
    float sa = 0.f, sb = 0.f;
#pragma unroll
    for (int d = 0; d < DD; d++) { float zv = zr[d]; sa += zv * a[d]; sb += zv * b[d]; }
    el[i] = sa; er[i] = sb;
}

// ---------- degrees ----------
__global__ void k_deg(P p) {
    int e = blockIdx.x * blockDim.x + threadIdx.x;
    if (e >= EE) return;
    atomicAdd(&p.deg_i[p.dst[e]], 1);
    atomicAdd(&p.deg_o[p.src[e]], 1);
}

// ---------- exclusive scan (single block, deterministic) ----------
__global__ void k_scan(const int* __restrict__ deg, int* __restrict__ off, int n) {
    __shared__ int sums[256];
    int t = threadIdx.x;
    int per = (n + 255) / 256;
    int s0i = t * per, e0 = s0i + per; if (e0 > n) e0 = n; if (s0i > n) s0i = n;
    int s = 0;
    for (int i = s0i; i < e0; i++) s += deg[i];
    sums[t] = s;
    __syncthreads();
    if (t == 0) {
        int acc = 0;
        for (int i = 0; i < 256; i++) { int v = sums[i]; sums[i] = acc; acc += v; }
        off[n] = acc;
    }
    __syncthreads();
    int acc = sums[t];
    for (int i = s0i; i < e0; i++) { off[i] = acc; acc += deg[i]; }
}

// ---------- CSR scatter (layer 0: all edges, by dst) ----------
__global__ void k_scatter0(P p) {
    int e = blockIdx.x * blockDim.x + threadIdx.x;
    if (e >= EE) return;
    int d = p.dst[e];
    int pos = p.off0[d] + atomicAdd(&p.cur0[d], 1);
    p.csr_eid[pos] = e;
    p.csr_src[pos] = p.src[e];
}

// ---------- layer-0 edge softmax passes ----------
__global__ void k_emax0(P p) {
    int e = blockIdx.x * blockDim.x + threadIdx.x;
    if (e >= EE) return;
    int s = p.src[e], d = p.dst[e];
    float4 es = *(const float4*)(p.el0 + s * 4);
    float4 ed = *(const float4*)(p.er0 + d * 4);
    atomicMax(&p.m0k[d * 4 + 0], fkey(lrelu(es.x + ed.x)));
    atomicMax(&p.m0k[d * 4 + 1], fkey(lrelu(es.y + ed.y)));
    atomicMax(&p.m0k[d * 4 + 2], fkey(lrelu(es.z + ed.z)));
    atomicMax(&p.m0k[d * 4 + 3], fkey(lrelu(es.w + ed.w)));
}
__global__ void k_esum0(P p) {
    int e = blockIdx.x * blockDim.x + threadIdx.x;
    if (e >= EE) return;
    int s = p.src[e], d = p.dst[e];
    float4 es = *(const float4*)(p.el0 + s * 4);
    float4 ed = *(const float4*)(p.er0 + d * 4);
    float l[4] = {lrelu(es.x + ed.x), lrelu(es.y + ed.y), lrelu(es.z + ed.z), lrelu(es.w + ed.w)};
#pragma unroll
    for (int h = 0; h < 4; h++) {
        float m = unfkey(p.m0k[d * 4 + h]);
        atomicAdd(&p.s0[d * 4 + h], (double)expf(l[h] - m));
    }
}
__global__ void k_ealpha0(P p) {
    int e = blockIdx.x * blockDim.x + threadIdx.x;
    if (e >= EE) return;
    int s = p.src[e], d = p.dst[e];
    float4 es = *(const float4*)(p.el0 + s * 4);
    float4 ed = *(const float4*)(p.er0 + d * 4);
    float l[4] = {lrelu(es.x + ed.x), lrelu(es.y + ed.y), lrelu(es.z + ed.z), lrelu(es.w + ed.w)};
#pragma unroll
    for (int h = 0; h < 4; h++) {
        float m = unfkey(p.m0k[d * 4 + h]);
        float ex = expf(l[h] - m);
        p.alpha0[e * 4 + h] = ex / fmaxf((float)p.s0[d * 4 + h], 1e-16f);
    }
}

// ---------- layer-0 aggregate: x[v] = sum alpha*z0[src] + b0 ----------
__global__ __launch_bounds__(128) void k_gather0(P p) {
    int v = blockIdx.x, c = threadIdx.x, h = c >> 5;
    int b = p.off0[v], en = p.off0[v + 1];
    double acc = 0.0;
    for (int i = b; i < en; i++) {
        int eid = p.csr_eid[i], s = p.csr_src[i];
        acc += (double)p.alpha0[eid * 4 + h] * (double)p.z0[(size_t)s * HD + c];
    }
    p.x[(size_t)v * HD + c] = (float)acc + p.b0[c];
}

// ---------- SAGPool score ----------
__global__ void k_hc(P p) {   // one wave per node: hc[v] = (x[v].Wc0) * deg_o^-0.5
    int gt = blockIdx.x * blockDim.x + threadIdx.x;
    int wid = gt >> 6, lane = gt & 63;
    if (wid >= NN) return;
    const float* xr = p.x + (size_t)wid * HD;
    float s = xr[lane] * p.Wc0[lane] + xr[lane + 64] * p.Wc0[lane + 64];
#pragma unroll
    for (int o = 32; o > 0; o >>= 1) s += __shfl_down(s, o);
    if (lane == 0) {
        float dg = fmaxf((float)p.deg_o[wid], 1.f);
        p.hc[wid] = s / sqrtf(dg);
    }
}
__global__ void k_score(P p) {
    int v = blockIdx.x * blockDim.x + threadIdx.x;
    if (v >= NN) return;
    int b = p.off0[v], en = p.off0[v + 1];
    float acc = 0.f;
    for (int i = b; i < en; i++) acc += p.hc[p.csr_src[i]];
    float dg = fmaxf((float)p.deg_i[v], 1.f);
    float sc = acc / sqrtf(dg) + p.bc0[0];
    p.score[v] = sc;
    p.keys[v] = fkey(sc);
}

// ---------- radix select (K-th largest key) ----------
__global__ void k_hist(P p, int pass) {
    int v = blockIdx.x * blockDim.x + threadIdx.x;
    if (v >= NN) return;
    unsigned key = p.keys[v];
    unsigned maskhi = pass ? (0xFFFFFFFFu << (32 - 8 * pass)) : 0u;
    unsigned pref = pass ? p.rs[0] : 0u;
    if ((key & maskhi) == (pref & maskhi))
        atomicAdd(&p.bins[(key >> (24 - 8 * pass)) & 255u], 1u);
}
__global__ void k_rsel(P p, int pass) {
    if (threadIdx.x | blockIdx.x) return;
    unsigned pref = pass ? p.rs[0] : 0u;
    int rem = pass ? (int)p.rs[1] : KK;
    int cum = 0;
    for (int b = 255; b >= 0; b--) {
        int c = (int)p.bins[b];
        if (cum + c >= rem) { pref |= ((unsigned)b) << (24 - 8 * pass); rem -= cum; break; }
        cum += c;
    }
    p.rs[0] = pref;
    p.rs[1] = (unsigned)rem;
    for (int i = 0; i < 256; i++) p.bins[i] = 0;
}
__global__ void k_sel(P p) {
    int v = blockIdx.x * blockDim.x + threadIdx.x;
    if (v >= NN) return;
    p.sel[v] = (p.keys[v] > p.rs[0]) ? 1 : 0;
}
__global__ __launch_bounds__(256) void k_ties(P p) {   // lowest-index ties (matches top_k)
    __shared__ int base;
    __shared__ int wsums[4];
    unsigned pivot = p.rs[0];
    int need = (int)p.rs[1];
    if (threadIdx.x == 0) base = 0;
    __syncthreads();
    for (int st = 0; st < NN; st += 256) {
        int v = st + threadIdx.x;
        int flag = (v < NN && p.keys[v] == pivot) ? 1 : 0;
        unsigned long long m = __ballot(flag);
        int lane = threadIdx.x & 63, w = threadIdx.x >> 6;
        int pre = __popcll(m & ((1ull << lane) - 1ull));
        if (lane == 0) wsums[w] = __popcll(m);
        __syncthreads();
        int woff = 0;
        for (int i = 0; i < w; i++) woff += wsums[i];
        int rank = base + woff + pre;
        if (flag && rank < need) p.sel[v] = 1;
        __syncthreads();
        if (threadIdx.x == 0) base += wsums[0] + wsums[1] + wsums[2] + wsums[3];
        __syncthreads();
    }
}
__global__ void k_list(P p) {
    int v = blockIdx.x * blockDim.x + threadIdx.x;
    if (v >= NN) return;
    if (p.sel[v]) {
        int i = atomicAdd(p.cnt, 1);
        p.list[i] = v;
        p.slot[v] = i;
        p.tscale[i] = tanhf(p.score[v]);
    } else {
        p.slot[v] = -1;
    }
}
__global__ void k_xk(P p) {
    int gid = blockIdx.x * blockDim.x + threadIdx.x;
    if (gid >= KK * HD) return;
    int i = gid >> 7, c = gid & 127;
    int v = p.list[i];
    p.xk[(size_t)i * HD + c] = p.x[(size_t)v * HD + c] * p.tscale[i];
}

// ---------- layer-1 graph (valid edges only, slot-indexed) ----------
__global__ void k_deg1(P p) {
    int e = blockIdx.x * blockDim.x + threadIdx.x;
    if (e >= EE) return;
    int ds = p.slot[p.src[e]], dd = p.slot[p.dst[e]];
    if (ds >= 0 && dd >= 0) atomicAdd(&p.deg1[dd], 1);
}
__global__ void k_scatter1(P p) {
    int e = blockIdx.x * blockDim.x + threadIdx.x;
    if (e >= EE) return;
    int ds = p.slot[p.src[e]], dd = p.slot[p.dst[e]];
    if (ds >= 0 && dd >= 0) {
        int pos = p.off1[dd] + atomicAdd(&p.cur1[dd], 1);
        p.csr_eid[pos] = e;
        p.csr_src[pos] = ds;
    }
}
__global__ void k_emax1(P p) {
    int e = blockIdx.x * blockDim.x + threadIdx.x;
    if (e >= EE) return;
    int ds = p.slot[p.src[e]], dd = p.slot[p.dst[e]];
    if (ds < 0 || dd < 0) return;
    float4 es = *(const float4*)(p.el1 + ds * 4);
    float4 ed = *(const float4*)(p.er1 + dd * 4);
    atomicMax(&p.m1k[dd * 4 + 0], fkey(lrelu(es.x + ed.x)));
    atomicMax(&p.m1k[dd * 4 + 1], fkey(lrelu(es.y + ed.y)));
    atomicMax(&p.m1k[dd * 4 + 2], fkey(lrelu(es.z + ed.z)));
    atomicMax(&p.m1k[dd * 4 + 3], fkey(lrelu(es.w + ed.w)));
}
__global__ void k_esum1(P p) {
    int e = blockIdx.x * blockDim.x + threadIdx.x;
    if (e >= EE) return;
    int ds = p.slot[p.src[e]], dd = p.slot[p.dst[e]];
    if (ds < 0 || dd < 0) return;
    float4 es = *(const float4*)(p.el1 + ds * 4);
    float4 ed = *(const float4*)(p.er1 + dd * 4);
    float l[4] = {lrelu(es.x + ed.x), lrelu(es.y + ed.y), lrelu(es.z + ed.z), lrelu(es.w + ed.w)};
#pragma unroll
    for (int h = 0; h < 4; h++) {
        float m = unfkey(p.m1k[dd * 4 + h]);
        atomicAdd(&p.s1[dd * 4 + h], (double)expf(l[h] - m));
    }
}
__global__ void k_ealpha1(P p) {   // writes atten + strength1 for ALL edges
    int e = blockIdx.x * blockDim.x + threadIdx.x;
    if (e >= EE) return;
    int ds = p.slot[p.src[e]], dd = p.slot[p.dst[e]];
    float a[4] = {0.f, 0.f, 0.f, 0.f};
    float st = 0.f;
    if (ds >= 0 && dd >= 0) {
        float4 es = *(const float4*)(p.el1 + ds * 4);
        float4 ed = *(const float4*)(p.er1 + dd * 4);
        float l[4] = {lrelu(es.x + ed.x), lrelu(es.y + ed.y), lrelu(es.z + ed.z), lrelu(es.w + ed.w)};
#pragma unroll
        for (int h = 0; h < 4; h++) {
            float m = unfkey(p.m1k[dd * 4 + h]);
            float ex = expf(l[h] - m);
            a[h] = ex / fmaxf((float)p.s1[dd * 4 + h], 1e-16f);
        }
        st = p.strength[e];
    }
    float* o = p.out + ATT_OFF + (size_t)e * 4;
    o[0] = a[0]; o[1] = a[1]; o[2] = a[2]; o[3] = a[3];
    p.out[STR_OFF + e] = st;
}
__global__ __launch_bounds__(128) void k_gather1(P p) {
    int i = blockIdx.x, c = threadIdx.x, h = c >> 5;
    int b = p.off1[i], en = p.off1[i + 1];
    double acc = 0.0;
    for (int j = b; j < en; j++) {
        int eid = p.csr_eid[j], s = p.csr_src[j];
        acc += (double)p.out[ATT_OFF + (size_t)eid * 4 + h] * (double)p.z1[(size_t)s * HD + c];
    }
    p.out1[(size_t)i * HD + c] = (float)acc + p.b1[c];
}

// ---------- readout ----------
__global__ void k_res(P p) {
    int gid = blockIdx.x * blockDim.x + threadIdx.x;
    if (gid >= KK * DD) return;
    int i = gid >> 5, d = gid & 31;
    const float* o = p.out1 + (size_t)i * HD;
    p.res[gid] = 0.25f * (o[d] + o[32 + d] + o[64 + d] + o[96 + d]);
}
__global__ void k_g(P p) {
    int i = blockIdx.x * blockDim.x + threadIdx.x;
    if (i >= KK) return;
    const float* r = p.res + (size_t)i * DD;
    float acc = 0.f;
#pragma unroll
    for (int d = 0; d < DD; d++) acc += r[d] * p.gW[d];
    p.g[i] = acc + p.gb[0];
}
__global__ void k_gmax(P p) {
    __shared__ float red[256];
    int t = threadIdx.x;
    float m = -3.4e38f;
    for (int i = blockIdx.x * 256 + t; i < KK; i += gridDim.x * 256) m = fmaxf(m, p.g[i]);
    red[t] = m;
    __syncthreads();
    for (int o = 128; o > 0; o >>= 1) { if (t < o) red[t] = fmaxf(red[t], red[t + o]); __syncthreads(); }
    if (t == 0) atomicMax(p.gmaxk, fkey(red[0]));
}
__global__ void k_wsum(P p) {
    __shared__ float vals[256];
    __shared__ float wv[8];
    int t = threadIdx.x, il = t >> 5, d = t & 31;
    int i = blockIdx.x * 8 + il;
    float gm = unfkey(*p.gmaxk);
    float w = expf(p.g[i] - gm);
    vals[t] = w * p.res[(size_t)i * DD + d];
    if (d == 0) wv[il] = w;
    __syncthreads();
    if (t < 32) {
        float s = 0.f;
#pragma unroll
        for (int k2 = 0; k2 < 8; k2++) s += vals[k2 * 32 + t];
        atomicAdd(&p.racc[t], (double)s);
    }
    if (t == 32) {
        float s = 0.f;
#pragma unroll
        for (int k2 = 0; k2 < 8; k2++) s += wv[k2];
        atomicAdd(p.Zacc, (double)s);
    }
}
__global__ void k_final(P p) {
    __shared__ float rb[32];
    int t = threadIdx.x;
    double Z = *p.Zacc;
    if (t < 32) {
        float r = (float)(p.racc[t] / Z);
        p.out[t] = r;
        rb[t] = r;
    }
    __syncthreads();
    if (t < 2) {
        float s = 0.f;
        for (int d = 0; d < 32; d++) s += rb[d] * p.cW[d * 2 + t];
        p.out[32 + t] = s + p.cb[t];
    }
}

// ---------- host ----------
extern "C" void kernel_launch(void* const* d_in, const int* in_sizes, int n_in,
                              void* d_out, int out_size, void* d_ws, size_t ws_size,
                              hipStream_t stream) {
    (void)in_sizes; (void)n_in; (void)out_size; (void)ws_size;
    P p;
    p.feature  = (const float*)d_in[0];
    p.strength = (const float*)d_in[1];
    p.W0  = (const float*)d_in[2];  p.b0  = (const float*)d_in[3];
    p.al0 = (const float*)d_in[4];  p.ar0 = (const float*)d_in[5];
    p.Wc0 = (const float*)d_in[6];  p.bc0 = (const float*)d_in[7];
    p.W1  = (const float*)d_in[8];  p.b1  = (const float*)d_in[9];
    p.al1 = (const float*)d_in[10]; p.ar1 = (const float*)d_in[11];
    p.gW  = (const float*)d_in[12]; p.gb  = (const float*)d_in[13];
    p.cW  = (const float*)d_in[14]; p.cb  = (const float*)d_in[15];
    p.src = (const int*)d_in[16];   p.dst = (const int*)d_in[17];
    p.out = (float*)d_out;

    char* ws = (char*)d_ws;
    size_t off = 0;
    auto alloc = [&](size_t bytes) -> void* {
        void* r = ws + off;
        off = (off + bytes + 255) & ~(size_t)255;
        return r;
    };
    // ---- zeroed region (must stay first/contiguous) ----
    p.s0    = (double*)alloc((size_t)NN * 4 * 8);
    p.s1    = (double*)alloc((size_t)KK * 4 * 8);
    p.Zacc  = (double*)alloc(8);
    p.racc  = (double*)alloc(32 * 8);
    p.deg_i = (int*)alloc((size_t)NN * 4);
    p.deg_o = (int*)alloc((size_t)NN * 4);
    p.cur0  = (int*)alloc((size_t)NN * 4);
    p.deg1  = (int*)alloc((size_t)KK * 4);
    p.cur1  = (int*)alloc((size_t)KK * 4);
    p.bins  = (unsigned*)alloc(256 * 4);
    p.cnt   = (int*)alloc(4);
    p.gmaxk = (unsigned*)alloc(4);
    p.rs    = (unsigned*)alloc(8);
    size_t zbytes = off;
    // ---- big buffers (with lifetime-based overlays) ----
    p.z0     = (float*)alloc((size_t)NN * HD * 4);   // later reused as out1
    p.out1   = p.z0;
    p.x      = (float*)alloc((size_t)NN * HD * 4);   // later reused as z1
    p.z1     = p.x;
    p.alpha0 = (float*)alloc((size_t)EE * 4 * 4);    // later reused as xk
    p.xk     = p.alpha0;
    p.csr_eid = (int*)alloc((size_t)EE * 4);         // shared by layer0/layer1 CSR
    p.csr_src = (int*)alloc((size_t)EE * 4);
    p.el0 = (float*)alloc((size_t)NN * 4 * 4);
    p.er0 = (float*)alloc((size_t)NN * 4 * 4);
    p.m0k = (unsigned*)alloc((size_t)NN * 4 * 4);
    p.off0 = (int*)alloc((size_t)(NN + 1) * 4);
    p.off1 = (int*)alloc((size_t)(KK + 1) * 4);
    p.hc    = (float*)alloc((size_t)NN * 4);
    p.score = (float*)alloc((size_t)NN * 4);
    p.keys  = (unsigned*)alloc((size_t)NN * 4);
    p.sel   = (int*)alloc((size_t)NN * 4);
    p.slot  = (int*)alloc((size_t)NN * 4);
    p.list  = (int*)alloc((size_t)KK * 4);
    p.tscale = (float*)alloc((size_t)KK * 4);
    p.el1 = (float*)alloc((size_t)KK * 4 * 4);
    p.er1 = (float*)alloc((size_t)KK * 4 * 4);
    p.m1k = (unsigned*)alloc((size_t)KK * 4 * 4);
    p.res = (float*)alloc((size_t)KK * DD * 4);
    p.g   = (float*)alloc((size_t)KK * 4);

    const int GB_E  = (EE + 255) / 256;        // 3125
    const int GB_N  = (NN + 255) / 256;        // 196
    const int GB_N4 = (NN * 4 + 255) / 256;    // 782
    const int GB_K  = (KK + 255) / 256;        // 98
    const int GB_K4 = (KK * 4 + 255) / 256;    // 391

    hipMemsetAsync(d_ws, 0, zbytes, stream);
    k_init<<<GB_N4, 256, 0, stream>>>(p);

    // ---- GAT layer 0 ----
    k_gemm<<<dim3(HD / BN, (NN + BM - 1) / BM), 256, 0, stream>>>(p.feature, p.W0, p.z0, NN, HD, FIN);
    k_elr<<<GB_N4, 256, 0, stream>>>(p.z0, p.al0, p.ar0, p.el0, p.er0, NN);
    k_deg<<<GB_E, 256, 0, stream>>>(p);
    k_scan<<<1, 256, 0, stream>>>(p.deg_i, p.off0, NN);
    k_scatter0<<<GB_E, 256, 0, stream>>>(p);
    k_emax0<<<GB_E, 256, 0, stream>>>(p);
    k_esum0<<<GB_E, 256, 0, stream>>>(p);
    k_ealpha0<<<GB_E, 256, 0, stream>>>(p);
    k_gather0<<<NN, 128, 0, stream>>>(p);

    // ---- SAGPool ----
    k_hc<<<(NN * 64 + 255) / 256, 256, 0, stream>>>(p);
    k_score<<<GB_N, 256, 0, stream>>>(p);
    for (int pass = 0; pass < 4; pass++) {
        k_hist<<<GB_N, 256, 0, stream>>>(p, pass);
        k_rsel<<<1, 1, 0, stream>>>(p, pass);
    }
    k_sel<<<GB_N, 256, 0, stream>>>(p);
    k_ties<<<1, 256, 0, stream>>>(p);
    k_list<<<GB_N, 256, 0, stream>>>(p);
    k_xk<<<(KK * HD + 255) / 256, 256, 0, stream>>>(p);

    // ---- GAT layer 1 ----
    k_gemm<<<dim3(HD / BN, (KK + BM - 1) / BM), 256, 0, stream>>>(p.xk, p.W1, p.z1, KK, HD, HD);
    k_elr<<<GB_K4, 256, 0, stream>>>(p.z1, p.al1, p.ar1, p.el1, p.er1, KK);
    k_deg1<<<GB_E, 256, 0, stream>>>(p);
    k_scan<<<1, 256, 0, stream>>>(p.deg1, p.off1, KK);
    k_scatter1<<<GB_E, 256, 0, stream>>>(p);
    k_emax1<<<GB_E, 256, 0, stream>>>(p);
    k_esum1<<<GB_E, 256, 0, stream>>>(p);
    k_ealpha1<<<GB_E, 256, 0, stream>>>(p);
    k_gather1<<<KK, 128, 0, stream>>>(p);

    // ---- readout ----
    k_res<<<(KK * DD + 255) / 256, 256, 0, stream>>>(p);
    k_g<<<GB_K, 256, 0, stream>>>(p);
    k_gmax<<<GB_K, 256, 0, stream>>>(p);
    k_wsum<<<KK / 8, 256, 0, stream>>>(p);
    k_final<<<1, 64, 0, stream>>>(p);
}

// Round 2
// 1210.991 us; speedup vs baseline: 1.3084x; 1.3084x over previous
//
#include <hip/hip_runtime.h>
#include <stdint.h>

#define NN 50000
#define EE 800000
#define FIN 256
#define HD 128
#define DD 32
#define KK 25000
#define SLOPEF 0.4f
#define NEGF (-1e9f)
#define ATT_OFF 34
#define STR_OFF (34 + EE * 4)

// ---------- helpers ----------
__device__ __forceinline__ unsigned fkey(float x) {
    unsigned u = __float_as_uint(x);
    return (u & 0x80000000u) ? ~u : (u | 0x80000000u);   // monotone float->uint
}
__device__ __forceinline__ float unfkey(unsigned k) {
    unsigned u = (k & 0x80000000u) ? (k ^ 0x80000000u) : ~k;
    return __uint_as_float(u);
}
__device__ __forceinline__ float lrelu(float v) { return v > 0.f ? v : SLOPEF * v; }

// ---------- pointer bundle ----------
struct P {
    // inputs
    const float *feature, *strength, *W0, *b0, *al0, *ar0, *Wc0, *bc0;
    const float *W1, *b1, *al1, *ar1, *gW, *gb, *cW, *cb;
    const int *src, *dst;
    // zeroed scratch
    double *s0, *s1, *Zacc, *racc;
    int *deg_i, *deg_o, *cur0, *deg1, *cur1, *cnt;
    unsigned *bins, *gmaxk, *rs;      // rs[0]=prefix/pivot, rs[1]=remaining/needTies
    // other scratch
    unsigned *m0k, *m1k, *keys;
    int *csr_eid, *csr_src, *off0, *off1, *sel, *slot, *list;
    float *z0, *x, *alpha0, *el0, *er0, *hc, *score, *xk, *z1;
    float *el1, *er1, *out1, *res, *g, *tscale;
    float *out;                        // d_out (float32)
};

// ---------- init m-keys ----------
__global__ void k_init(P p) {
    int i = blockIdx.x * blockDim.x + threadIdx.x;
    unsigned v = fkey(NEGF);
    if (i < NN * 4) p.m0k[i] = v;
    if (i < KK * 4) p.m1k[i] = v;
}

// ---------- fp32 tiled GEMM: C[M,Nd] = A[M,Kd] @ B[Kd,Nd] ----------
#define BM 64
#define BN 64
#define BK 16
__global__ __launch_bounds__(256) void k_gemm(const float* __restrict__ A,
                                              const float* __restrict__ B,
                                              float* __restrict__ C,
                                              int M, int Nd, int Kd) {
    __shared__ float As[BK][BM + 1];
    __shared__ float Bs[BK][BN];
    int bm = blockIdx.y * BM, bn = blockIdx.x * BN;
    int tid = threadIdx.x;
    int tr = tid >> 4, tc = tid & 15;  // 16x16 threads, each 4x4
    float acc[4][4] = {};
    for (int k0 = 0; k0 < Kd; k0 += BK) {
        {   // A tile: 64 rows x 16 k
            int row = tid >> 2, col = (tid & 3) << 2;
            int gr = bm + row;
            float4 v = {0.f, 0.f, 0.f, 0.f};
            if (gr < M) v = *(const float4*)(A + (size_t)gr * Kd + k0 + col);
            As[col + 0][row] = v.x; As[col + 1][row] = v.y;
            As[col + 2][row] = v.z; As[col + 3][row] = v.w;
        }
        {   // B tile: 16 k x 64 cols
            int kr = tid >> 4, col = (tid & 15) << 2;
            float4 v = *(const float4*)(B + (size_t)(k0 + kr) * Nd + bn + col);
            *(float4*)&Bs[kr][col] = v;
        }
        __syncthreads();
#pragma unroll
        for (int kk = 0; kk < BK; kk++) {
            float a[4], b[4];
#pragma unroll
            for (int i = 0; i < 4; i++) a[i] = As[kk][tr * 4 + i];
#pragma unroll
            for (int j = 0; j < 4; j++) b[j] = Bs[kk][tc * 4 + j];
#pragma unroll
            for (int i = 0; i < 4; i++)
#pragma unroll
                for (int j = 0; j < 4; j++) acc[i][j] += a[i] * b[j];
        }
        __syncthreads();
    }
#pragma unroll
    for (int i = 0; i < 4; i++) {
        int gr = bm + tr * 4 + i;
        if (gr < M) {
            float4 v = {acc[i][0], acc[i][1], acc[i][2], acc[i][3]};
            *(float4*)(C + (size_t)gr * Nd + bn + tc * 4) = v;
        }
    }
}

// ---------- per-(node,head) attn logits el/er ----------
__global__ void k_elr(const float* __restrict__ z, const float* __restrict__ al,
                      const float* __restrict__ ar, float* __restrict__ el,
                      float* __restrict__ er, int n) {
    int i = blockIdx.x * blockDim.x + threadIdx.x;
    if (i >= n * 4) return;
    int v = i >> 2, h = i & 3;
    const float* zr = z + (size_t)v * HD + h * DD;
    const float* a = al + h * DD;
    const float* b = ar + h * DD;
    float sa = 0.f, sb = 0.f;
#pragma unroll
    for (int d = 0; d < DD; d++) { float zv = zr[d]; sa += zv * a[d]; sb += zv * b[d]; }
    el[i] = sa; er[i] = sb;
}

// ---------- degrees ----------
__global__ void k_deg(P p) {
    int e = blockIdx.x * blockDim.x + threadIdx.x;
    if (e >= EE) return;
    atomicAdd(&p.deg_i[p.dst[e]], 1);
    atomicAdd(&p.deg_o[p.src[e]], 1);
}

// ---------- exclusive scan (single block, deterministic) ----------
__global__ void k_scan(const int* __restrict__ deg, int* __restrict__ off, int n) {
    __shared__ int sums[256];
    int t = threadIdx.x;
    int per = (n + 255) / 256;
    int s0i = t * per, e0 = s0i + per; if (e0 > n) e0 = n; if (s0i > n) s0i = n;
    int s = 0;
    for (int i = s0i; i < e0; i++) s += deg[i];
    sums[t] = s;
    __syncthreads();
    if (t == 0) {
        int acc = 0;
        for (int i = 0; i < 256; i++) { int v = sums[i]; sums[i] = acc; acc += v; }
        off[n] = acc;
    }
    __syncthreads();
    int acc = sums[t];
    for (int i = s0i; i < e0; i++) { off[i] = acc; acc += deg[i]; }
}

// ---------- CSR scatter (layer 0: all edges, by dst) ----------
__global__ void k_scatter0(P p) {
    int e = blockIdx.x * blockDim.x + threadIdx.x;
    if (e >= EE) return;
    int d = p.dst[e];
    int pos = p.off0[d] + atomicAdd(&p.cur0[d], 1);
    p.csr_eid[pos] = e;
    p.csr_src[pos] = p.src[e];
}

// ---------- layer-0 edge softmax passes ----------
__global__ void k_emax0(P p) {
    int e = blockIdx.x * blockDim.x + threadIdx.x;
    if (e >= EE) return;
    int s = p.src[e], d = p.dst[e];
    float4 es = *(const float4*)(p.el0 + s * 4);
    float4 ed = *(const float4*)(p.er0 + d * 4);
    atomicMax(&p.m0k[d * 4 + 0], fkey(lrelu(es.x + ed.x)));
    atomicMax(&p.m0k[d * 4 + 1], fkey(lrelu(es.y + ed.y)));
    atomicMax(&p.m0k[d * 4 + 2], fkey(lrelu(es.z + ed.z)));
    atomicMax(&p.m0k[d * 4 + 3], fkey(lrelu(es.w + ed.w)));
}
__global__ void k_esum0(P p) {
    int e = blockIdx.x * blockDim.x + threadIdx.x;
    if (e >= EE) return;
    int s = p.src[e], d = p.dst[e];
    float4 es = *(const float4*)(p.el0 + s * 4);
    float4 ed = *(const float4*)(p.er0 + d * 4);
    float l[4] = {lrelu(es.x + ed.x), lrelu(es.y + ed.y), lrelu(es.z + ed.z), lrelu(es.w + ed.w)};
#pragma unroll
    for (int h = 0; h < 4; h++) {
        float m = unfkey(p.m0k[d * 4 + h]);
        atomicAdd(&p.s0[d * 4 + h], (double)expf(l[h] - m));
    }
}
__global__ void k_ealpha0(P p) {
    int e = blockIdx.x * blockDim.x + threadIdx.x;
    if (e >= EE) return;
    int s = p.src[e], d = p.dst[e];
    float4 es = *(const float4*)(p.el0 + s * 4);
    float4 ed = *(const float4*)(p.er0 + d * 4);
    float l[4] = {lrelu(es.x + ed.x), lrelu(es.y + ed.y), lrelu(es.z + ed.z), lrelu(es.w + ed.w)};
#pragma unroll
    for (int h = 0; h < 4; h++) {
        float m = unfkey(p.m0k[d * 4 + h]);
        float ex = expf(l[h] - m);
        p.alpha0[e * 4 + h] = ex / fmaxf((float)p.s0[d * 4 + h], 1e-16f);
    }
}

// ---------- layer-0 aggregate: x[v] = sum alpha*z0[src] + b0 ----------
__global__ __launch_bounds__(128) void k_gather0(P p) {
    int v = blockIdx.x, c = threadIdx.x, h = c >> 5;
    int b = p.off0[v], en = p.off0[v + 1];
    double acc = 0.0;
    for (int i = b; i < en; i++) {
        int eid = p.csr_eid[i], s = p.csr_src[i];
        acc += (double)p.alpha0[eid * 4 + h] * (double)p.z0[(size_t)s * HD + c];
    }
    p.x[(size_t)v * HD + c] = (float)acc + p.b0[c];
}

// ---------- SAGPool score ----------
__global__ void k_hc(P p) {   // one wave per node: hc[v] = (x[v].Wc0) * deg_o^-0.5
    int gt = blockIdx.x * blockDim.x + threadIdx.x;
    int wid = gt >> 6, lane = gt & 63;
    if (wid >= NN) return;
    const float* xr = p.x + (size_t)wid * HD;
    float s = xr[lane] * p.Wc0[lane] + xr[lane + 64] * p.Wc0[lane + 64];
#pragma unroll
    for (int o = 32; o > 0; o >>= 1) s += __shfl_down(s, o);
    if (lane == 0) {
        float dg = fmaxf((float)p.deg_o[wid], 1.f);
        p.hc[wid] = s / sqrtf(dg);
    }
}
__global__ void k_score(P p) {
    int v = blockIdx.x * blockDim.x + threadIdx.x;
    if (v >= NN) return;
    int b = p.off0[v], en = p.off0[v + 1];
    float acc = 0.f;
    for (int i = b; i < en; i++) acc += p.hc[p.csr_src[i]];
    float dg = fmaxf((float)p.deg_i[v], 1.f);
    float sc = acc / sqrtf(dg) + p.bc0[0];
    p.score[v] = sc;
    p.keys[v] = fkey(sc);
}

// ---------- radix select (K-th largest key) ----------
// LDS histogram first: 50k global atomics on 2-4 hot addresses serialized at
// ~250us/pass in R1 (G12 violation). Per-block LDS bins -> <=100 global
// adds/bin spread over 256 addresses.
#define HIST_BLOCKS 100
__global__ __launch_bounds__(256) void k_hist(P p, int pass) {
    __shared__ unsigned hb[256];
    hb[threadIdx.x] = 0;
    __syncthreads();
    unsigned maskhi = pass ? (0xFFFFFFFFu << (32 - 8 * pass)) : 0u;
    unsigned pref = pass ? (p.rs[0] & maskhi) : 0u;
    int shift = 24 - 8 * pass;
    for (int v = blockIdx.x * 256 + threadIdx.x; v < NN; v += HIST_BLOCKS * 256) {
        unsigned key = p.keys[v];
        if ((key & maskhi) == pref)
            atomicAdd(&hb[(key >> shift) & 255u], 1u);
    }
    __syncthreads();
    unsigned c = hb[threadIdx.x];
    if (c) atomicAdd(&p.bins[threadIdx.x], c);
}
__global__ __launch_bounds__(256) void k_rsel(P p, int pass) {
    __shared__ unsigned c[256];
    __shared__ unsigned sfx[257];
    int t = threadIdx.x;
    c[t] = p.bins[t];
    p.bins[t] = 0;                       // reset for next pass
    __syncthreads();
    if (t == 0) {                        // 256-iter LDS loop: ~1k cycles, fine
        unsigned acc = 0;
        sfx[256] = 0;
        for (int b = 255; b >= 0; b--) { acc += c[b]; sfx[b] = acc; }
    }
    __syncthreads();
    unsigned pref = pass ? p.rs[0] : 0u;
    int rem = pass ? (int)p.rs[1] : KK;
    if ((int)sfx[t] >= rem && (int)sfx[t + 1] < rem) {   // unique t
        p.rs[0] = pref | ((unsigned)t << (24 - 8 * pass));
        p.rs[1] = (unsigned)(rem - (int)sfx[t + 1]);
    }
}
__global__ void k_sel(P p) {
    int v = blockIdx.x * blockDim.x + threadIdx.x;
    if (v >= NN) return;
    p.sel[v] = (p.keys[v] > p.rs[0]) ? 1 : 0;
}
__global__ __launch_bounds__(1024) void k_ties(P p) {   // lowest-index ties (matches top_k)
    __shared__ int base;
    __shared__ int wsums[16];
    unsigned pivot = p.rs[0];
    int need = (int)p.rs[1];
    if (threadIdx.x == 0) base = 0;
    __syncthreads();
    for (int st = 0; st < NN; st += 1024) {
        int v = st + (int)threadIdx.x;
        int flag = (v < NN && p.keys[v] == pivot) ? 1 : 0;
        unsigned long long m = __ballot(flag);
        int lane = threadIdx.x & 63, w = threadIdx.x >> 6;
        int pre = __popcll(m & ((1ull << lane) - 1ull));
        if (lane == 0) wsums[w] = __popcll(m);
        __syncthreads();
        int woff = 0;
        for (int i = 0; i < w; i++) woff += wsums[i];
        int rank = base + woff + pre;
        if (flag && rank < need) p.sel[v] = 1;
        __syncthreads();
        if (threadIdx.x == 0) {
            int s = 0;
            for (int i = 0; i < 16; i++) s += wsums[i];
            base += s;
        }
        __syncthreads();
    }
}
__global__ void k_list(P p) {
    int v = blockIdx.x * blockDim.x + threadIdx.x;
    if (v >= NN) return;
    if (p.sel[v]) {
        int i = atomicAdd(p.cnt, 1);
        p.list[i] = v;
        p.slot[v] = i;
        p.tscale[i] = tanhf(p.score[v]);
    } else {
        p.slot[v] = -1;
    }
}
__global__ void k_xk(P p) {
    int gid = blockIdx.x * blockDim.x + threadIdx.x;
    if (gid >= KK * HD) return;
    int i = gid >> 7, c = gid & 127;
    int v = p.list[i];
    p.xk[(size_t)i * HD + c] = p.x[(size_t)v * HD + c] * p.tscale[i];
}

// ---------- layer-1 graph (valid edges only, slot-indexed) ----------
__global__ void k_deg1(P p) {
    int e = blockIdx.x * blockDim.x + threadIdx.x;
    if (e >= EE) return;
    int ds = p.slot[p.src[e]], dd = p.slot[p.dst[e]];
    if (ds >= 0 && dd >= 0) atomicAdd(&p.deg1[dd], 1);
}
__global__ void k_scatter1(P p) {
    int e = blockIdx.x * blockDim.x + threadIdx.x;
    if (e >= EE) return;
    int ds = p.slot[p.src[e]], dd = p.slot[p.dst[e]];
    if (ds >= 0 && dd >= 0) {
        int pos = p.off1[dd] + atomicAdd(&p.cur1[dd], 1);
        p.csr_eid[pos] = e;
        p.csr_src[pos] = ds;
    }
}
__global__ void k_emax1(P p) {
    int e = blockIdx.x * blockDim.x + threadIdx.x;
    if (e >= EE) return;
    int ds = p.slot[p.src[e]], dd = p.slot[p.dst[e]];
    if (ds < 0 || dd < 0) return;
    float4 es = *(const float4*)(p.el1 + ds * 4);
    float4 ed = *(const float4*)(p.er1 + dd * 4);
    atomicMax(&p.m1k[dd * 4 + 0], fkey(lrelu(es.x + ed.x)));
    atomicMax(&p.m1k[dd * 4 + 1], fkey(lrelu(es.y + ed.y)));
    atomicMax(&p.m1k[dd * 4 + 2], fkey(lrelu(es.z + ed.z)));
    atomicMax(&p.m1k[dd * 4 + 3], fkey(lrelu(es.w + ed.w)));
}
__global__ void k_esum1(P p) {
    int e = blockIdx.x * blockDim.x + threadIdx.x;
    if (e >= EE) return;
    int ds = p.slot[p.src[e]], dd = p.slot[p.dst[e]];
    if (ds < 0 || dd < 0) return;
    float4 es = *(const float4*)(p.el1 + ds * 4);
    float4 ed = *(const float4*)(p.er1 + dd * 4);
    float l[4] = {lrelu(es.x + ed.x), lrelu(es.y + ed.y), lrelu(es.z + ed.z), lrelu(es.w + ed.w)};
#pragma unroll
    for (int h = 0; h < 4; h++) {
        float m = unfkey(p.m1k[dd * 4 + h]);
        atomicAdd(&p.s1[dd * 4 + h], (double)expf(l[h] - m));
    }
}
__global__ void k_ealpha1(P p) {   // writes atten + strength1 for ALL edges
    int e = blockIdx.x * blockDim.x + threadIdx.x;
    if (e >= EE) return;
    int ds = p.slot[p.src[e]], dd = p.slot[p.dst[e]];
    float a[4] = {0.f, 0.f, 0.f, 0.f};
    float st = 0.f;
    if (ds >= 0 && dd >= 0) {
        float4 es = *(const float4*)(p.el1 + ds * 4);
        float4 ed = *(const float4*)(p.er1 + dd * 4);
        float l[4] = {lrelu(es.x + ed.x), lrelu(es.y + ed.y), lrelu(es.z + ed.z), lrelu(es.w + ed.w)};
#pragma unroll
        for (int h = 0; h < 4; h++) {
            float m = unfkey(p.m1k[dd * 4 + h]);
            float ex = expf(l[h] - m);
            a[h] = ex / fmaxf((float)p.s1[dd * 4 + h], 1e-16f);
        }
        st = p.strength[e];
    }
    float* o = p.out + ATT_OFF + (size_t)e * 4;
    o[0] = a[0]; o[1] = a[1]; o[2] = a[2]; o[3] = a[3];
    p.out[STR_OFF + e] = st;
}
__global__ __launch_bounds__(128) void k_gather1(P p) {
    int i = blockIdx.x, c = threadIdx.x, h = c >> 5;
    int b = p.off1[i], en = p.off1[i + 1];
    double acc = 0.0;
    for (int j = b; j < en; j++) {
        int eid = p.csr_eid[j], s = p.csr_src[j];
        acc += (double)p.out[ATT_OFF + (size_t)eid * 4 + h] * (double)p.z1[(size_t)s * HD + c];
    }
    p.out1[(size_t)i * HD + c] = (float)acc + p.b1[c];
}

// ---------- readout ----------
__global__ void k_res(P p) {
    int gid = blockIdx.x * blockDim.x + threadIdx.x;
    if (gid >= KK * DD) return;
    int i = gid >> 5, d = gid & 31;
    const float* o = p.out1 + (size_t)i * HD;
    p.res[gid] = 0.25f * (o[d] + o[32 + d] + o[64 + d] + o[96 + d]);
}
__global__ void k_g(P p) {
    int i = blockIdx.x * blockDim.x + threadIdx.x;
    if (i >= KK) return;
    const float* r = p.res + (size_t)i * DD;
    float acc = 0.f;
#pragma unroll
    for (int d = 0; d < DD; d++) acc += r[d] * p.gW[d];
    p.g[i] = acc + p.gb[0];
}
__global__ void k_gmax(P p) {
    __shared__ float red[256];
    int t = threadIdx.x;
    float m = -3.4e38f;
    for (int i = blockIdx.x * 256 + t; i < KK; i += gridDim.x * 256) m = fmaxf(m, p.g[i]);
    red[t] = m;
    __syncthreads();
    for (int o = 128; o > 0; o >>= 1) { if (t < o) red[t] = fmaxf(red[t], red[t + o]); __syncthreads(); }
    if (t == 0) atomicMax(p.gmaxk, fkey(red[0]));
}
__global__ void k_wsum(P p) {
    __shared__ float vals[256];
    __shared__ float wv[8];
    int t = threadIdx.x, il = t >> 5, d = t & 31;
    int i = blockIdx.x * 8 + il;
    float gm = unfkey(*p.gmaxk);
    float w = expf(p.g[i] - gm);
    vals[t] = w * p.res[(size_t)i * DD + d];
    if (d == 0) wv[il] = w;
    __syncthreads();
    if (t < 32) {
        float s = 0.f;
#pragma unroll
        for (int k2 = 0; k2 < 8; k2++) s += vals[k2 * 32 + t];
        atomicAdd(&p.racc[t], (double)s);
    }
    if (t == 32) {
        float s = 0.f;
#pragma unroll
        for (int k2 = 0; k2 < 8; k2++) s += wv[k2];
        atomicAdd(p.Zacc, (double)s);
    }
}
__global__ void k_final(P p) {
    __shared__ float rb[32];
    int t = threadIdx.x;
    double Z = *p.Zacc;
    if (t < 32) {
        float r = (float)(p.racc[t] / Z);
        p.out[t] = r;
        rb[t] = r;
    }
    __syncthreads();
    if (t < 2) {
        float s = 0.f;
        for (int d = 0; d < 32; d++) s += rb[d] * p.cW[d * 2 + t];
        p.out[32 + t] = s + p.cb[t];
    }
}

// ---------- host ----------
extern "C" void kernel_launch(void* const* d_in, const int* in_sizes, int n_in,
                              void* d_out, int out_size, void* d_ws, size_t ws_size,
                              hipStream_t stream) {
    (void)in_sizes; (void)n_in; (void)out_size; (void)ws_size;
    P p;
    p.feature  = (const float*)d_in[0];
    p.strength = (const float*)d_in[1];
    p.W0  = (const float*)d_in[2];  p.b0  = (const float*)d_in[3];
    p.al0 = (const float*)d_in[4];  p.ar0 = (const float*)d_in[5];
    p.Wc0 = (const float*)d_in[6];  p.bc0 = (const float*)d_in[7];
    p.W1  = (const float*)d_in[8];  p.b1  = (const float*)d_in[9];
    p.al1 = (const float*)d_in[10]; p.ar1 = (const float*)d_in[11];
    p.gW  = (const float*)d_in[12]; p.gb  = (const float*)d_in[13];
    p.cW  = (const float*)d_in[14]; p.cb  = (const float*)d_in[15];
    p.src = (const int*)d_in[16];   p.dst = (const int*)d_in[17];
    p.out = (float*)d_out;

    char* ws = (char*)d_ws;
    size_t off = 0;
    auto alloc = [&](size_t bytes) -> void* {
        void* r = ws + off;
        off = (off + bytes + 255) & ~(size_t)255;
        return r;
    };
    // ---- zeroed region (must stay first/contiguous) ----
    p.s0    = (double*)alloc((size_t)NN * 4 * 8);
    p.s1    = (double*)alloc((size_t)KK * 4 * 8);
    p.Zacc  = (double*)alloc(8);
    p.racc  = (double*)alloc(32 * 8);
    p.deg_i = (int*)alloc((size_t)NN * 4);
    p.deg_o = (int*)alloc((size_t)NN * 4);
    p.cur0  = (int*)alloc((size_t)NN * 4);
    p.deg1  = (int*)alloc((size_t)KK * 4);
    p.cur1  = (int*)alloc((size_t)KK * 4);
    p.bins  = (unsigned*)alloc(256 * 4);
    p.cnt   = (int*)alloc(4);
    p.gmaxk = (unsigned*)alloc(4);
    p.rs    = (unsigned*)alloc(8);
    size_t zbytes = off;
    // ---- big buffers (with lifetime-based overlays) ----
    p.z0     = (float*)alloc((size_t)NN * HD * 4);   // later reused as out1
    p.out1   = p.z0;
    p.x      = (float*)alloc((size_t)NN * HD * 4);   // later reused as z1
    p.z1     = p.x;
    p.alpha0 = (float*)alloc((size_t)EE * 4 * 4);    // later reused as xk
    p.xk     = p.alpha0;
    p.csr_eid = (int*)alloc((size_t)EE * 4);         // shared by layer0/layer1 CSR
    p.csr_src = (int*)alloc((size_t)EE * 4);
    p.el0 = (float*)alloc((size_t)NN * 4 * 4);
    p.er0 = (float*)alloc((size_t)NN * 4 * 4);
    p.m0k = (unsigned*)alloc((size_t)NN * 4 * 4);
    p.off0 = (int*)alloc((size_t)(NN + 1) * 4);
    p.off1 = (int*)alloc((size_t)(KK + 1) * 4);
    p.hc    = (float*)alloc((size_t)NN * 4);
    p.score = (float*)alloc((size_t)NN * 4);
    p.keys  = (unsigned*)alloc((size_t)NN * 4);
    p.sel   = (int*)alloc((size_t)NN * 4);
    p.slot  = (int*)alloc((size_t)NN * 4);
    p.list  = (int*)alloc((size_t)KK * 4);
    p.tscale = (float*)alloc((size_t)KK * 4);
    p.el1 = (float*)alloc((size_t)KK * 4 * 4);
    p.er1 = (float*)alloc((size_t)KK * 4 * 4);
    p.m1k = (unsigned*)alloc((size_t)KK * 4 * 4);
    p.res = (float*)alloc((size_t)KK * DD * 4);
    p.g   = (float*)alloc((size_t)KK * 4);

    const int GB_E  = (EE + 255) / 256;        // 3125
    const int GB_N  = (NN + 255) / 256;        // 196
    const int GB_N4 = (NN * 4 + 255) / 256;    // 782
    const int GB_K  = (KK + 255) / 256;        // 98
    const int GB_K4 = (KK * 4 + 255) / 256;    // 391

    hipMemsetAsync(d_ws, 0, zbytes, stream);
    k_init<<<GB_N4, 256, 0, stream>>>(p);

    // ---- GAT layer 0 ----
    k_gemm<<<dim3(HD / BN, (NN + BM - 1) / BM), 256, 0, stream>>>(p.feature, p.W0, p.z0, NN, HD, FIN);
    k_elr<<<GB_N4, 256, 0, stream>>>(p.z0, p.al0, p.ar0, p.el0, p.er0, NN);
    k_deg<<<GB_E, 256, 0, stream>>>(p);
    k_scan<<<1, 256, 0, stream>>>(p.deg_i, p.off0, NN);
    k_scatter0<<<GB_E, 256, 0, stream>>>(p);
    k_emax0<<<GB_E, 256, 0, stream>>>(p);
    k_esum0<<<GB_E, 256, 0, stream>>>(p);
    k_ealpha0<<<GB_E, 256, 0, stream>>>(p);
    k_gather0<<<NN, 128, 0, stream>>>(p);

    // ---- SAGPool ----
    k_hc<<<(NN * 64 + 255) / 256, 256, 0, stream>>>(p);
    k_score<<<GB_N, 256, 0, stream>>>(p);
    for (int pass = 0; pass < 4; pass++) {
        k_hist<<<HIST_BLOCKS, 256, 0, stream>>>(p, pass);
        k_rsel<<<1, 256, 0, stream>>>(p, pass);
    }
    k_sel<<<GB_N, 256, 0, stream>>>(p);
    k_ties<<<1, 1024, 0, stream>>>(p);
    k_list<<<GB_N, 256, 0, stream>>>(p);
    k_xk<<<(KK * HD + 255) / 256, 256, 0, stream>>>(p);

    // ---- GAT layer 1 ----
    k_gemm<<<dim3(HD / BN, (KK + BM - 1) / BM), 256, 0, stream>>>(p.xk, p.W1, p.z1, KK, HD, HD);
    k_elr<<<GB_K4, 256, 0, stream>>>(p.z1, p.al1, p.ar1, p.el1, p.er1, KK);
    k_deg1<<<GB_E, 256, 0, stream>>>(p);
    k_scan<<<1, 256, 0, stream>>>(p.deg1, p.off1, KK);
    k_scatter1<<<GB_E, 256, 0, stream>>>(p);
    k_emax1<<<GB_E, 256, 0, stream>>>(p);
    k_esum1<<<GB_E, 256, 0, stream>>>(p);
    k_ealpha1<<<GB_E, 256, 0, stream>>>(p);
    k_gather1<<<KK, 128, 0, stream>>>(p);

    // ---- readout ----
    k_res<<<(KK * DD + 255) / 256, 256, 0, stream>>>(p);
    k_g<<<GB_K, 256, 0, stream>>>(p);
    k_gmax<<<GB_K, 256, 0, stream>>>(p);
    k_wsum<<<KK / 8, 256, 0, stream>>>(p);
    k_final<<<1, 64, 0, stream>>>(p);
}

// Round 3
// 862.076 us; speedup vs baseline: 1.8379x; 1.4047x over previous
//
#include <hip/hip_runtime.h>
#include <stdint.h>

#define NN 50000
#define EE 800000
#define FIN 256
#define HD 128
#define DD 32
#define KK 25000
#define SLOPEF 0.4f
#define NEGF (-1e9f)
#define ATT_OFF 34
#define STR_OFF (34 + EE * 4)

// ---------- helpers ----------
__device__ __forceinline__ unsigned fkey(float x) {
    unsigned u = __float_as_uint(x);
    return (u & 0x80000000u) ? ~u : (u | 0x80000000u);   // monotone float->uint
}
__device__ __forceinline__ float unfkey(unsigned k) {
    unsigned u = (k & 0x80000000u) ? (k ^ 0x80000000u) : ~k;
    return __uint_as_float(u);
}
__device__ __forceinline__ float lrelu(float v) { return v > 0.f ? v : SLOPEF * v; }

// ---------- pointer bundle ----------
struct P {
    // inputs
    const float *feature, *strength, *W0, *b0, *al0, *ar0, *Wc0, *bc0;
    const float *W1, *b1, *al1, *ar1, *gW, *gb, *cW, *cb;
    const int *src, *dst;
    // zeroed scratch
    double *Zacc, *racc;
    int *deg_i, *deg_o, *cur0, *deg1, *cur1, *cnt;
    unsigned *bins, *gmaxk, *rs;      // rs[0]=prefix/pivot, rs[1]=remaining
    // other scratch
    unsigned *keys;
    int *csr_src, *off0, *off1, *sel, *slot, *list;
    float *z0, *x, *alphaC, *el0, *er0, *hc, *score, *xk, *z1;
    float *el1, *er1, *m1f, *s1f, *out1, *res, *g, *tscale;
    float *out;                        // d_out (float32)
};

// ---------- fp32 tiled GEMM: C[M,Nd] = A[M,Kd] @ B[Kd,Nd] ----------
#define BM 64
#define BN 64
#define BK 16
__global__ __launch_bounds__(256) void k_gemm(const float* __restrict__ A,
                                              const float* __restrict__ B,
                                              float* __restrict__ C,
                                              int M, int Nd, int Kd) {
    __shared__ float As[BK][BM + 1];
    __shared__ float Bs[BK][BN];
    int bm = blockIdx.y * BM, bn = blockIdx.x * BN;
    int tid = threadIdx.x;
    int tr = tid >> 4, tc = tid & 15;  // 16x16 threads, each 4x4
    float acc[4][4] = {};
    for (int k0 = 0; k0 < Kd; k0 += BK) {
        {   // A tile: 64 rows x 16 k
            int row = tid >> 2, col = (tid & 3) << 2;
            int gr = bm + row;
            float4 v = {0.f, 0.f, 0.f, 0.f};
            if (gr < M) v = *(const float4*)(A + (size_t)gr * Kd + k0 + col);
            As[col + 0][row] = v.x; As[col + 1][row] = v.y;
            As[col + 2][row] = v.z; As[col + 3][row] = v.w;
        }
        {   // B tile: 16 k x 64 cols
            int kr = tid >> 4, col = (tid & 15) << 2;
            float4 v = *(const float4*)(B + (size_t)(k0 + kr) * Nd + bn + col);
            *(float4*)&Bs[kr][col] = v;
        }
        __syncthreads();
#pragma unroll
        for (int kk = 0; kk < BK; kk++) {
            float a[4], b[4];
#pragma unroll
            for (int i = 0; i < 4; i++) a[i] = As[kk][tr * 4 + i];
#pragma unroll
            for (int j = 0; j < 4; j++) b[j] = Bs[kk][tc * 4 + j];
#pragma unroll
            for (int i = 0; i < 4; i++)
#pragma unroll
                for (int j = 0; j < 4; j++) acc[i][j] += a[i] * b[j];
        }
        __syncthreads();
    }
#pragma unroll
    for (int i = 0; i < 4; i++) {
        int gr = bm + tr * 4 + i;
        if (gr < M) {
            float4 v = {acc[i][0], acc[i][1], acc[i][2], acc[i][3]};
            *(float4*)(C + (size_t)gr * Nd + bn + tc * 4) = v;
        }
    }
}

// ---------- per-(node,head) attn logits el/er ----------
__global__ void k_elr(const float* __restrict__ z, const float* __restrict__ al,
                      const float* __restrict__ ar, float* __restrict__ el,
                      float* __restrict__ er, int n) {
    int i = blockIdx.x * blockDim.x + threadIdx.x;
    if (i >= n * 4) return;
    int v = i >> 2, h = i & 3;
    const float* zr = z + (size_t)v * HD + h * DD;
    const float* a = al + h * DD;
    const float* b = ar + h * DD;
    float sa = 0.f, sb = 0.f;
#pragma unroll
    for (int d = 0; d < DD; d++) { float zv = zr[d]; sa += zv * a[d]; sb += zv * b[d]; }
    el[i] = sa; er[i] = sb;
}

// ---------- degrees ----------
__global__ void k_deg(P p) {
    int e = blockIdx.x * blockDim.x + threadIdx.x;
    if (e >= EE) return;
    atomicAdd(&p.deg_i[p.dst[e]], 1);
    atomicAdd(&p.deg_o[p.src[e]], 1);
}

// ---------- exclusive scan (single block, deterministic) ----------
__global__ void k_scan(const int* __restrict__ deg, int* __restrict__ off, int n) {
    __shared__ int sums[256];
    int t = threadIdx.x;
    int per = (n + 255) / 256;
    int s0i = t * per, e0 = s0i + per; if (e0 > n) e0 = n; if (s0i > n) s0i = n;
    int s = 0;
    for (int i = s0i; i < e0; i++) s += deg[i];
    sums[t] = s;
    __syncthreads();
    if (t == 0) {
        int acc = 0;
        for (int i = 0; i < 256; i++) { int v = sums[i]; sums[i] = acc; acc += v; }
        off[n] = acc;
    }
    __syncthreads();
    int acc = sums[t];
    for (int i = s0i; i < e0; i++) { off[i] = acc; acc += deg[i]; }
}

// ---------- CSR scatter (src-ids only; eid no longer needed) ----------
__global__ void k_scatter0(P p) {
    int e = blockIdx.x * blockDim.x + threadIdx.x;
    if (e >= EE) return;
    int d = p.dst[e];
    int pos = p.off0[d] + atomicAdd(&p.cur0[d], 1);
    p.csr_src[pos] = p.src[e];
}

// ---------- CSR edge softmax: per-(node,head), NO atomics ----------
// R2 post-mortem: 3.2M scattered fp64/u32 atomics -> 100MB write-through at
// ~21G atomics/s = ~300us across 4 kernels. CSR gather replaces them all.
// Two-pass (exact max, then fp64-accumulated sum of fp32 exps) matches the
// reference's segment_max/segment_sum semantics order-insensitively.
__global__ __launch_bounds__(256) void k_msum(const int* __restrict__ off,
                                              const int* __restrict__ csrs,
                                              const float* __restrict__ el,
                                              const float* __restrict__ er,
                                              float* __restrict__ alphaC,
                                              float* __restrict__ mf,
                                              float* __restrict__ sf, int n) {
    int i = blockIdx.x * blockDim.x + threadIdx.x;
    if (i >= n * 4) return;
    int v = i >> 2, h = i & 3;
    int b = off[v], e = off[v + 1];
    float erv = er[i];
    float m = NEGF;
    for (int j = b; j < e; j++)
        m = fmaxf(m, lrelu(el[csrs[j] * 4 + h] + erv));
    double s = 0.0;
    for (int j = b; j < e; j++) {
        float ex = expf(lrelu(el[csrs[j] * 4 + h] + erv) - m);
        s += (double)ex;
        alphaC[j * 4 + h] = ex;
    }
    float sv = (float)s;
    float inv = 1.f / fmaxf(sv, 1e-16f);
    for (int j = b; j < e; j++) alphaC[j * 4 + h] *= inv;
    if (mf) { mf[i] = m; sf[i] = sv; }
}

// ---------- layer-0 aggregate: x[v] = sum alpha*z0[src] + b0 ----------
__global__ __launch_bounds__(128) void k_gather0(P p) {
    int v = blockIdx.x, c = threadIdx.x, h = c >> 5;
    int b = p.off0[v], en = p.off0[v + 1];
    double acc = 0.0;
    for (int i = b; i < en; i++) {
        int s = p.csr_src[i];
        acc += (double)p.alphaC[i * 4 + h] * (double)p.z0[(size_t)s * HD + c];
    }
    p.x[(size_t)v * HD + c] = (float)acc + p.b0[c];
}

// ---------- SAGPool score ----------
__global__ void k_hc(P p) {   // one wave per node: hc[v] = (x[v].Wc0) * deg_o^-0.5
    int gt = blockIdx.x * blockDim.x + threadIdx.x;
    int wid = gt >> 6, lane = gt & 63;
    if (wid >= NN) return;
    const float* xr = p.x + (size_t)wid * HD;
    float s = xr[lane] * p.Wc0[lane] + xr[lane + 64] * p.Wc0[lane + 64];
#pragma unroll
    for (int o = 32; o > 0; o >>= 1) s += __shfl_down(s, o);
    if (lane == 0) {
        float dg = fmaxf((float)p.deg_o[wid], 1.f);
        p.hc[wid] = s / sqrtf(dg);
    }
}
__global__ void k_score(P p) {
    int v = blockIdx.x * blockDim.x + threadIdx.x;
    if (v >= NN) return;
    int b = p.off0[v], en = p.off0[v + 1];
    float acc = 0.f;
    for (int i = b; i < en; i++) acc += p.hc[p.csr_src[i]];
    float dg = fmaxf((float)p.deg_i[v], 1.f);
    float sc = acc / sqrtf(dg) + p.bc0[0];
    p.score[v] = sc;
    p.keys[v] = fkey(sc);
}

// ---------- radix select (K-th largest key) ----------
#define HIST_BLOCKS 100
__global__ __launch_bounds__(256) void k_hist(P p, int pass) {
    __shared__ unsigned hb[256];
    hb[threadIdx.x] = 0;
    __syncthreads();
    unsigned maskhi = pass ? (0xFFFFFFFFu << (32 - 8 * pass)) : 0u;
    unsigned pref = pass ? (p.rs[0] & maskhi) : 0u;
    int shift = 24 - 8 * pass;
    for (int v = blockIdx.x * 256 + threadIdx.x; v < NN; v += HIST_BLOCKS * 256) {
        unsigned key = p.keys[v];
        if ((key & maskhi) == pref)
            atomicAdd(&hb[(key >> shift) & 255u], 1u);
    }
    __syncthreads();
    unsigned c = hb[threadIdx.x];
    if (c) atomicAdd(&p.bins[threadIdx.x], c);
}
__global__ __launch_bounds__(256) void k_rsel(P p, int pass) {
    __shared__ unsigned c[256];
    __shared__ unsigned sfx[257];
    int t = threadIdx.x;
    c[t] = p.bins[t];
    p.bins[t] = 0;                       // reset for next pass
    __syncthreads();
    if (t == 0) {
        unsigned acc = 0;
        sfx[256] = 0;
        for (int b = 255; b >= 0; b--) { acc += c[b]; sfx[b] = acc; }
    }
    __syncthreads();
    unsigned pref = pass ? p.rs[0] : 0u;
    int rem = pass ? (int)p.rs[1] : KK;
    if ((int)sfx[t] >= rem && (int)sfx[t + 1] < rem) {   // unique t
        p.rs[0] = pref | ((unsigned)t << (24 - 8 * pass));
        p.rs[1] = (unsigned)(rem - (int)sfx[t + 1]);
    }
}
__global__ void k_sel(P p) {
    int v = blockIdx.x * blockDim.x + threadIdx.x;
    if (v >= NN) return;
    p.sel[v] = (p.keys[v] > p.rs[0]) ? 1 : 0;
}
__global__ __launch_bounds__(1024) void k_ties(P p) {   // lowest-index ties (matches top_k)
    __shared__ int base;
    __shared__ int wsums[16];
    unsigned pivot = p.rs[0];
    int need = (int)p.rs[1];
    if (threadIdx.x == 0) base = 0;
    __syncthreads();
    for (int st = 0; st < NN; st += 1024) {
        int v = st + (int)threadIdx.x;
        int flag = (v < NN && p.keys[v] == pivot) ? 1 : 0;
        unsigned long long m = __ballot(flag);
        int lane = threadIdx.x & 63, w = threadIdx.x >> 6;
        int pre = __popcll(m & ((1ull << lane) - 1ull));
        if (lane == 0) wsums[w] = __popcll(m);
        __syncthreads();
        int woff = 0;
        for (int i = 0; i < w; i++) woff += wsums[i];
        int rank = base + woff + pre;
        if (flag && rank < need) p.sel[v] = 1;
        __syncthreads();
        if (threadIdx.x == 0) {
            int s = 0;
            for (int i = 0; i < 16; i++) s += wsums[i];
            base += s;
        }
        __syncthreads();
    }
}
__global__ void k_list(P p) {
    int v = blockIdx.x * blockDim.x + threadIdx.x;
    if (v >= NN) return;
    if (p.sel[v]) {
        int i = atomicAdd(p.cnt, 1);
        p.list[i] = v;
        p.slot[v] = i;
        p.tscale[i] = tanhf(p.score[v]);
    } else {
        p.slot[v] = -1;
    }
}
__global__ void k_xk(P p) {
    int gid = blockIdx.x * blockDim.x + threadIdx.x;
    if (gid >= KK * HD) return;
    int i = gid >> 7, c = gid & 127;
    int v = p.list[i];
    p.xk[(size_t)i * HD + c] = p.x[(size_t)v * HD + c] * p.tscale[i];
}

// ---------- layer-1 graph (valid edges only, slot-indexed) ----------
__global__ void k_deg1(P p) {
    int e = blockIdx.x * blockDim.x + threadIdx.x;
    if (e >= EE) return;
    int ds = p.slot[p.src[e]], dd = p.slot[p.dst[e]];
    if (ds >= 0 && dd >= 0) atomicAdd(&p.deg1[dd], 1);
}
__global__ void k_scatter1(P p) {
    int e = blockIdx.x * blockDim.x + threadIdx.x;
    if (e >= EE) return;
    int ds = p.slot[p.src[e]], dd = p.slot[p.dst[e]];
    if (ds >= 0 && dd >= 0) {
        int pos = p.off1[dd] + atomicAdd(&p.cur1[dd], 1);
        p.csr_src[pos] = ds;
    }
}
// per-edge alpha for output: pure reads, writes atten+strength for ALL edges
__global__ void k_ealpha1(P p) {
    int e = blockIdx.x * blockDim.x + threadIdx.x;
    if (e >= EE) return;
    int ds = p.slot[p.src[e]], dd = p.slot[p.dst[e]];
    float a[4] = {0.f, 0.f, 0.f, 0.f};
    float st = 0.f;
    if (ds >= 0 && dd >= 0) {
        float4 es = *(const float4*)(p.el1 + ds * 4);
        float4 ed = *(const float4*)(p.er1 + dd * 4);
        float l[4] = {lrelu(es.x + ed.x), lrelu(es.y + ed.y), lrelu(es.z + ed.z), lrelu(es.w + ed.w)};
#pragma unroll
        for (int h = 0; h < 4; h++) {
            float m = p.m1f[dd * 4 + h];
            float ex = expf(l[h] - m);
            a[h] = ex / fmaxf(p.s1f[dd * 4 + h], 1e-16f);
        }
        st = p.strength[e];
    }
    float* o = p.out + ATT_OFF + (size_t)e * 4;
    o[0] = a[0]; o[1] = a[1]; o[2] = a[2]; o[3] = a[3];
    p.out[STR_OFF + e] = st;
}
__global__ __launch_bounds__(128) void k_gather1(P p) {
    int i = blockIdx.x, c = threadIdx.x, h = c >> 5;
    int b = p.off1[i], en = p.off1[i + 1];
    double acc = 0.0;
    for (int j = b; j < en; j++) {
        int s = p.csr_src[j];
        acc += (double)p.alphaC[j * 4 + h] * (double)p.z1[(size_t)s * HD + c];
    }
    p.out1[(size_t)i * HD + c] = (float)acc + p.b1[c];
}

// ---------- readout ----------
__global__ void k_res(P p) {
    int gid = blockIdx.x * blockDim.x + threadIdx.x;
    if (gid >= KK * DD) return;
    int i = gid >> 5, d = gid & 31;
    const float* o = p.out1 + (size_t)i * HD;
    p.res[gid] = 0.25f * (o[d] + o[32 + d] + o[64 + d] + o[96 + d]);
}
__global__ void k_g(P p) {
    int i = blockIdx.x * blockDim.x + threadIdx.x;
    if (i >= KK) return;
    const float* r = p.res + (size_t)i * DD;
    float acc = 0.f;
#pragma unroll
    for (int d = 0; d < DD; d++) acc += r[d] * p.gW[d];
    p.g[i] = acc + p.gb[0];
}
__global__ void k_gmax(P p) {
    __shared__ float red[256];
    int t = threadIdx.x;
    float m = -3.4e38f;
    for (int i = blockIdx.x * 256 + t; i < KK; i += gridDim.x * 256) m = fmaxf(m, p.g[i]);
    red[t] = m;
    __syncthreads();
    for (int o = 128; o > 0; o >>= 1) { if (t < o) red[t] = fmaxf(red[t], red[t + o]); __syncthreads(); }
    if (t == 0) atomicMax(p.gmaxk, fkey(red[0]));   // memset-0 identity ok (only -NaN keys to 0)
}
__global__ void k_wsum(P p) {
    __shared__ float vals[256];
    __shared__ float wv[8];
    int t = threadIdx.x, il = t >> 5, d = t & 31;
    int i = blockIdx.x * 8 + il;
    float gm = unfkey(*p.gmaxk);
    float w = expf(p.g[i] - gm);
    vals[t] = w * p.res[(size_t)i * DD + d];
    if (d == 0) wv[il] = w;
    __syncthreads();
    if (t < 32) {
        float s = 0.f;
#pragma unroll
        for (int k2 = 0; k2 < 8; k2++) s += vals[k2 * 32 + t];
        atomicAdd(&p.racc[t], (double)s);
    }
    if (t == 32) {
        float s = 0.f;
#pragma unroll
        for (int k2 = 0; k2 < 8; k2++) s += wv[k2];
        atomicAdd(p.Zacc, (double)s);
    }
}
__global__ void k_final(P p) {
    __shared__ float rb[32];
    int t = threadIdx.x;
    double Z = *p.Zacc;
    if (t < 32) {
        float r = (float)(p.racc[t] / Z);
        p.out[t] = r;
        rb[t] = r;
    }
    __syncthreads();
    if (t < 2) {
        float s = 0.f;
        for (int d = 0; d < 32; d++) s += rb[d] * p.cW[d * 2 + t];
        p.out[32 + t] = s + p.cb[t];
    }
}

// ---------- host ----------
extern "C" void kernel_launch(void* const* d_in, const int* in_sizes, int n_in,
                              void* d_out, int out_size, void* d_ws, size_t ws_size,
                              hipStream_t stream) {
    (void)in_sizes; (void)n_in; (void)out_size; (void)ws_size;
    P p;
    p.feature  = (const float*)d_in[0];
    p.strength = (const float*)d_in[1];
    p.W0  = (const float*)d_in[2];  p.b0  = (const float*)d_in[3];
    p.al0 = (const float*)d_in[4];  p.ar0 = (const float*)d_in[5];
    p.Wc0 = (const float*)d_in[6];  p.bc0 = (const float*)d_in[7];
    p.W1  = (const float*)d_in[8];  p.b1  = (const float*)d_in[9];
    p.al1 = (const float*)d_in[10]; p.ar1 = (const float*)d_in[11];
    p.gW  = (const float*)d_in[12]; p.gb  = (const float*)d_in[13];
    p.cW  = (const float*)d_in[14]; p.cb  = (const float*)d_in[15];
    p.src = (const int*)d_in[16];   p.dst = (const int*)d_in[17];
    p.out = (float*)d_out;

    char* ws = (char*)d_ws;
    size_t off = 0;
    auto alloc = [&](size_t bytes) -> void* {
        void* r = ws + off;
        off = (off + bytes + 255) & ~(size_t)255;
        return r;
    };
    // ---- zeroed region (must stay first/contiguous) ----
    p.Zacc  = (double*)alloc(8);
    p.racc  = (double*)alloc(32 * 8);
    p.deg_i = (int*)alloc((size_t)NN * 4);
    p.deg_o = (int*)alloc((size_t)NN * 4);
    p.cur0  = (int*)alloc((size_t)NN * 4);
    p.deg1  = (int*)alloc((size_t)KK * 4);
    p.cur1  = (int*)alloc((size_t)KK * 4);
    p.bins  = (unsigned*)alloc(256 * 4);
    p.cnt   = (int*)alloc(4);
    p.gmaxk = (unsigned*)alloc(4);
    p.rs    = (unsigned*)alloc(8);
    size_t zbytes = off;
    // ---- big buffers (with lifetime-based overlays) ----
    p.z0     = (float*)alloc((size_t)NN * HD * 4);   // later reused as out1
    p.out1   = p.z0;
    p.x      = (float*)alloc((size_t)NN * HD * 4);   // later reused as z1
    p.z1     = p.x;
    p.alphaC = (float*)alloc((size_t)EE * 4 * 4);    // alphaC0 -> xk -> alphaC1
    p.xk     = p.alphaC;
    p.csr_src = (int*)alloc((size_t)EE * 4);
    p.el0 = (float*)alloc((size_t)NN * 4 * 4);
    p.er0 = (float*)alloc((size_t)NN * 4 * 4);
    p.off0 = (int*)alloc((size_t)(NN + 1) * 4);
    p.off1 = (int*)alloc((size_t)(KK + 1) * 4);
    p.hc    = (float*)alloc((size_t)NN * 4);
    p.score = (float*)alloc((size_t)NN * 4);
    p.keys  = (unsigned*)alloc((size_t)NN * 4);
    p.sel   = (int*)alloc((size_t)NN * 4);
    p.slot  = (int*)alloc((size_t)NN * 4);
    p.list  = (int*)alloc((size_t)KK * 4);
    p.tscale = (float*)alloc((size_t)KK * 4);
    p.el1 = (float*)alloc((size_t)KK * 4 * 4);
    p.er1 = (float*)alloc((size_t)KK * 4 * 4);
    p.m1f = (float*)alloc((size_t)KK * 4 * 4);
    p.s1f = (float*)alloc((size_t)KK * 4 * 4);
    p.res = (float*)alloc((size_t)KK * DD * 4);
    p.g   = (float*)alloc((size_t)KK * 4);

    const int GB_E  = (EE + 255) / 256;        // 3125
    const int GB_N  = (NN + 255) / 256;        // 196
    const int GB_N4 = (NN * 4 + 255) / 256;    // 782
    const int GB_K  = (KK + 255) / 256;        // 98
    const int GB_K4 = (KK * 4 + 255) / 256;    // 391

    hipMemsetAsync(d_ws, 0, zbytes, stream);

    // ---- GAT layer 0 ----
    k_gemm<<<dim3(HD / BN, (NN + BM - 1) / BM), 256, 0, stream>>>(p.feature, p.W0, p.z0, NN, HD, FIN);
    k_elr<<<GB_N4, 256, 0, stream>>>(p.z0, p.al0, p.ar0, p.el0, p.er0, NN);
    k_deg<<<GB_E, 256, 0, stream>>>(p);
    k_scan<<<1, 256, 0, stream>>>(p.deg_i, p.off0, NN);
    k_scatter0<<<GB_E, 256, 0, stream>>>(p);
    k_msum<<<GB_N4, 256, 0, stream>>>(p.off0, p.csr_src, p.el0, p.er0, p.alphaC,
                                      nullptr, nullptr, NN);
    k_gather0<<<NN, 128, 0, stream>>>(p);

    // ---- SAGPool ----
    k_hc<<<(NN * 64 + 255) / 256, 256, 0, stream>>>(p);
    k_score<<<GB_N, 256, 0, stream>>>(p);
    for (int pass = 0; pass < 4; pass++) {
        k_hist<<<HIST_BLOCKS, 256, 0, stream>>>(p, pass);
        k_rsel<<<1, 256, 0, stream>>>(p, pass);
    }
    k_sel<<<GB_N, 256, 0, stream>>>(p);
    k_ties<<<1, 1024, 0, stream>>>(p);
    k_list<<<GB_N, 256, 0, stream>>>(p);
    k_xk<<<(KK * HD + 255) / 256, 256, 0, stream>>>(p);

    // ---- GAT layer 1 ----
    k_gemm<<<dim3(HD / BN, (KK + BM - 1) / BM), 256, 0, stream>>>(p.xk, p.W1, p.z1, KK, HD, HD);
    k_elr<<<GB_K4, 256, 0, stream>>>(p.z1, p.al1, p.ar1, p.el1, p.er1, KK);
    k_deg1<<<GB_E, 256, 0, stream>>>(p);
    k_scan<<<1, 256, 0, stream>>>(p.deg1, p.off1, KK);
    k_scatter1<<<GB_E, 256, 0, stream>>>(p);
    k_msum<<<GB_K4, 256, 0, stream>>>(p.off1, p.csr_src, p.el1, p.er1, p.alphaC,
                                      p.m1f, p.s1f, KK);
    k_ealpha1<<<GB_E, 256, 0, stream>>>(p);
    k_gather1<<<KK, 128, 0, stream>>>(p);

    // ---- readout ----
    k_res<<<(KK * DD + 255) / 256, 256, 0, stream>>>(p);
    k_g<<<GB_K, 256, 0, stream>>>(p);
    k_gmax<<<GB_K, 256, 0, stream>>>(p);
    k_wsum<<<KK / 8, 256, 0, stream>>>(p);
    k_final<<<1, 64, 0, stream>>>(p);
}

// Round 4
// 738.824 us; speedup vs baseline: 2.1445x; 1.1668x over previous
//
#include <hip/hip_runtime.h>
#include <stdint.h>

#define NN 50000
#define EE 800000
#define FIN 256
#define HD 128
#define DD 32
#define KK 25000
#define SLOPEF 0.4f
#define NEGF (-1e9f)
#define ATT_OFF 34
#define STR_OFF (34 + EE * 4)
#define CAP 128            // LDS-cached edges per node (deg ~Poisson(16); P(deg>128)~0; recompute fallback kept)

// ---------- helpers ----------
__device__ __forceinline__ unsigned fkey(float x) {
    unsigned u = __float_as_uint(x);
    return (u & 0x80000000u) ? ~u : (u | 0x80000000u);   // monotone float->uint
}
__device__ __forceinline__ float unfkey(unsigned k) {
    unsigned u = (k & 0x80000000u) ? (k ^ 0x80000000u) : ~k;
    return __uint_as_float(u);
}
__device__ __forceinline__ float lrelu(float v) { return v > 0.f ? v : SLOPEF * v; }

// ---------- pointer bundle ----------
struct P {
    // inputs
    const float *feature, *strength, *W0, *b0, *al0, *ar0, *Wc0, *bc0;
    const float *W1, *b1, *al1, *ar1, *gW, *gb, *cW, *cb;
    const int *src, *dst;
    // zeroed scratch
    double *Zacc, *racc;
    int *deg_i, *deg_o, *cur0, *deg1, *cur1, *cnt;
    unsigned *bins, *gmaxk, *rs;      // rs[0]=prefix/pivot, rs[1]=remaining
    // other scratch
    unsigned *keys;
    int *csr_src, *off0, *off1, *sel, *slot, *list;
    float *z0, *x, *el0, *er0, *hc, *score, *xk, *z1;
    float *el1, *er1, *m1f, *s1f, *res, *g, *tscale;
    float *out;                        // d_out (float32)
};

// ---------- fp32 tiled GEMM: C[M,Nd] = A[M,Kd] @ B[Kd,Nd] ----------
#define BM 64
#define BN 64
#define BK 16
__global__ __launch_bounds__(256) void k_gemm(const float* __restrict__ A,
                                              const float* __restrict__ B,
                                              float* __restrict__ C,
                                              int M, int Nd, int Kd) {
    __shared__ float As[BK][BM + 1];
    __shared__ float Bs[BK][BN];
    int bm = blockIdx.y * BM, bn = blockIdx.x * BN;
    int tid = threadIdx.x;
    int tr = tid >> 4, tc = tid & 15;  // 16x16 threads, each 4x4
    float acc[4][4] = {};
    for (int k0 = 0; k0 < Kd; k0 += BK) {
        {   // A tile: 64 rows x 16 k
            int row = tid >> 2, col = (tid & 3) << 2;
            int gr = bm + row;
            float4 v = {0.f, 0.f, 0.f, 0.f};
            if (gr < M) v = *(const float4*)(A + (size_t)gr * Kd + k0 + col);
            As[col + 0][row] = v.x; As[col + 1][row] = v.y;
            As[col + 2][row] = v.z; As[col + 3][row] = v.w;
        }
        {   // B tile: 16 k x 64 cols
            int kr = tid >> 4, col = (tid & 15) << 2;
            float4 v = *(const float4*)(B + (size_t)(k0 + kr) * Nd + bn + col);
            *(float4*)&Bs[kr][col] = v;
        }
        __syncthreads();
#pragma unroll
        for (int kk = 0; kk < BK; kk++) {
            float a[4], b[4];
#pragma unroll
            for (int i = 0; i < 4; i++) a[i] = As[kk][tr * 4 + i];
#pragma unroll
            for (int j = 0; j < 4; j++) b[j] = Bs[kk][tc * 4 + j];
#pragma unroll
            for (int i = 0; i < 4; i++)
#pragma unroll
                for (int j = 0; j < 4; j++) acc[i][j] += a[i] * b[j];
        }
        __syncthreads();
    }
#pragma unroll
    for (int i = 0; i < 4; i++) {
        int gr = bm + tr * 4 + i;
        if (gr < M) {
            float4 v = {acc[i][0], acc[i][1], acc[i][2], acc[i][3]};
            *(float4*)(C + (size_t)gr * Nd + bn + tc * 4) = v;
        }
    }
}

// ---------- per-(node,head) attn logits el/er ----------
__global__ void k_elr(const float* __restrict__ z, const float* __restrict__ al,
                      const float* __restrict__ ar, float* __restrict__ el,
                      float* __restrict__ er, int n) {
    int i = blockIdx.x * blockDim.x + threadIdx.x;
    if (i >= n * 4) return;
    int v = i >> 2, h = i & 3;
    const float* zr = z + (size_t)v * HD + h * DD;
    const float* a = al + h * DD;
    const float* b = ar + h * DD;
    float sa = 0.f, sb = 0.f;
#pragma unroll
    for (int d = 0; d < DD; d++) { float zv = zr[d]; sa += zv * a[d]; sb += zv * b[d]; }
    el[i] = sa; er[i] = sb;
}

// ---------- degrees ----------
__global__ void k_deg(P p) {
    int e = blockIdx.x * blockDim.x + threadIdx.x;
    if (e >= EE) return;
    atomicAdd(&p.deg_i[p.dst[e]], 1);
    atomicAdd(&p.deg_o[p.src[e]], 1);
}

// ---------- exclusive scan (single block 1024, wave shfl-scan) ----------
__global__ __launch_bounds__(1024) void k_scan(const int* __restrict__ deg, int* __restrict__ off, int n) {
    __shared__ int ws[16];
    __shared__ int woff[17];
    int t = threadIdx.x;
    int per = (n + 1023) / 1024;
    int s0 = t * per; if (s0 > n) s0 = n;
    int e0 = s0 + per; if (e0 > n) e0 = n;
    int s = 0;
    for (int i = s0; i < e0; i++) s += deg[i];
    int lane = t & 63, w = t >> 6;
    int val = s;
    for (int o = 1; o < 64; o <<= 1) { int u = __shfl_up(val, o); if (lane >= o) val += u; }
    if (lane == 63) ws[w] = val;
    __syncthreads();
    if (t == 0) { int a = 0; for (int i = 0; i < 16; i++) { woff[i] = a; a += ws[i]; } woff[16] = a; }
    __syncthreads();
    if (t == 0) off[n] = woff[16];
    int acc = woff[w] + val - s;   // exclusive prefix
    for (int i = s0; i < e0; i++) { off[i] = acc; acc += deg[i]; }
}

// ---------- CSR scatter (src-ids only) ----------
__global__ void k_scatter0(P p) {
    int e = blockIdx.x * blockDim.x + threadIdx.x;
    if (e >= EE) return;
    int d = p.dst[e];
    int pos = p.off0[d] + atomicAdd(&p.cur0[d], 1);
    p.csr_src[pos] = p.src[e];
}

// ---------- FUSED GAT aggregate: softmax (max/sum) + weighted z-gather ----------
// One block (128 thr) per dst node. Phase 1-2 on wave 0 (deg avg 16 << 64):
// exact max then fp64-reduced exp-sum, exps cached in LDS. Phase 3 channel-
// parallel: acc_c = sum_j exp_j * z[s_j,c] (fp64 serial, order-stable), then
// x = acc/s + bias. Epilogues: EPI=1 -> hc[v] (SAGPool GraphConv h), EPI=2 ->
// res[v,:] + g[v] (head-mean + gate logit); out1 never materialized.
template <int EPI>
__global__ __launch_bounds__(128) void k_fgat(
    const int* __restrict__ off, const int* __restrict__ csrs,
    const float* __restrict__ el, const float* __restrict__ er,
    const float* __restrict__ z, const float* __restrict__ bias,
    float* __restrict__ xout, float* __restrict__ mf, float* __restrict__ sf,
    const float* __restrict__ Wc, const int* __restrict__ dego, float* __restrict__ hc,
    const float* __restrict__ gW, const float* __restrict__ gb,
    float* __restrict__ res, float* __restrict__ g) {
    int v = blockIdx.x;
    int b = off[v], e = off[v + 1], deg = e - b;
    __shared__ float4 sexp[CAP];
    __shared__ int ssrc[CAP];
    __shared__ float smh[4], ssh[4];
    __shared__ float lred[128];
    int tid = threadIdx.x;
    float4 er4 = *(const float4*)(er + (size_t)v * 4);
    if (tid < 64) {
        float m0 = NEGF, m1 = NEGF, m2 = NEGF, m3 = NEGF;
        for (int li = tid; li < deg; li += 64) {
            int s = csrs[b + li];
            if (li < CAP) ssrc[li] = s;
            float4 e4 = *(const float4*)(el + (size_t)s * 4);
            m0 = fmaxf(m0, lrelu(e4.x + er4.x));
            m1 = fmaxf(m1, lrelu(e4.y + er4.y));
            m2 = fmaxf(m2, lrelu(e4.z + er4.z));
            m3 = fmaxf(m3, lrelu(e4.w + er4.w));
        }
        for (int o = 32; o; o >>= 1) {
            m0 = fmaxf(m0, __shfl_down(m0, o));
            m1 = fmaxf(m1, __shfl_down(m1, o));
            m2 = fmaxf(m2, __shfl_down(m2, o));
            m3 = fmaxf(m3, __shfl_down(m3, o));
        }
        if (tid == 0) { smh[0] = m0; smh[1] = m1; smh[2] = m2; smh[3] = m3; }
    }
    __syncthreads();
    if (tid < 64) {
        float mm0 = smh[0], mm1 = smh[1], mm2 = smh[2], mm3 = smh[3];
        double s0 = 0, s1 = 0, s2 = 0, s3 = 0;
        for (int li = tid; li < deg; li += 64) {
            int s = (li < CAP) ? ssrc[li] : csrs[b + li];
            float4 e4 = *(const float4*)(el + (size_t)s * 4);
            float x0 = expf(lrelu(e4.x + er4.x) - mm0);
            float x1 = expf(lrelu(e4.y + er4.y) - mm1);
            float x2 = expf(lrelu(e4.z + er4.z) - mm2);
            float x3 = expf(lrelu(e4.w + er4.w) - mm3);
            if (li < CAP) { float4 t; t.x = x0; t.y = x1; t.z = x2; t.w = x3; sexp[li] = t; }
            s0 += (double)x0; s1 += (double)x1; s2 += (double)x2; s3 += (double)x3;
        }
        for (int o = 32; o; o >>= 1) {
            s0 += __shfl_down(s0, o); s1 += __shfl_down(s1, o);
            s2 += __shfl_down(s2, o); s3 += __shfl_down(s3, o);
        }
        if (tid == 0) { ssh[0] = (float)s0; ssh[1] = (float)s1; ssh[2] = (float)s2; ssh[3] = (float)s3; }
    }
    __syncthreads();
    if (mf && tid < 4) { mf[v * 4 + tid] = smh[tid]; sf[v * 4 + tid] = ssh[tid]; }
    // phase 3: channel-parallel weighted gather
    int c = tid, h = c >> 5;
    float mmh = smh[h];
    float erh = (h == 0) ? er4.x : (h == 1) ? er4.y : (h == 2) ? er4.z : er4.w;
    double acc = 0.0;
    for (int li = 0; li < deg; li++) {
        int s; float w;
        if (li < CAP) { s = ssrc[li]; w = ((const float*)&sexp[li])[h]; }
        else { s = csrs[b + li]; w = expf(lrelu(el[s * 4 + h] + erh) - mmh); }
        acc += (double)w * (double)z[(size_t)s * HD + c];
    }
    double sd = (double)ssh[h]; if (sd < 1e-16) sd = 1e-16;
    float xc = (float)(acc / sd) + bias[c];
    if (EPI == 1) {
        xout[(size_t)v * HD + c] = xc;
        float pc = xc * Wc[c];
        for (int o = 32; o; o >>= 1) pc += __shfl_down(pc, o);
        if ((tid & 63) == 0) lred[tid >> 6] = pc;
        __syncthreads();
        if (tid == 0) hc[v] = (lred[0] + lred[1]) / sqrtf(fmaxf((float)dego[v], 1.f));
    }
    if (EPI == 2) {
        lred[c] = xc;
        __syncthreads();
        if (c < 32) {
            float r = 0.25f * (lred[c] + lred[c + 32] + lred[c + 64] + lred[c + 96]);
            res[(size_t)v * 32 + c] = r;
            float pg = r * gW[c];
            for (int o = 16; o; o >>= 1) pg += __shfl_down(pg, o);
            if (c == 0) g[v] = pg + gb[0];
        }
    }
}

// ---------- SAGPool score ----------
__global__ void k_score(P p) {
    int v = blockIdx.x * blockDim.x + threadIdx.x;
    if (v >= NN) return;
    int b = p.off0[v], en = p.off0[v + 1];
    float acc = 0.f;
    for (int i = b; i < en; i++) acc += p.hc[p.csr_src[i]];
    float dg = fmaxf((float)p.deg_i[v], 1.f);
    float sc = acc / sqrtf(dg) + p.bc0[0];
    p.score[v] = sc;
    p.keys[v] = fkey(sc);
}

// ---------- radix select (K-th largest key) ----------
#define HIST_BLOCKS 100
__global__ __launch_bounds__(256) void k_hist(P p, int pass) {
    __shared__ unsigned hb[256];
    hb[threadIdx.x] = 0;
    __syncthreads();
    unsigned maskhi = pass ? (0xFFFFFFFFu << (32 - 8 * pass)) : 0u;
    unsigned pref = pass ? (p.rs[0] & maskhi) : 0u;
    int shift = 24 - 8 * pass;
    for (int v = blockIdx.x * 256 + threadIdx.x; v < NN; v += HIST_BLOCKS * 256) {
        unsigned key = p.keys[v];
        if ((key & maskhi) == pref)
            atomicAdd(&hb[(key >> shift) & 255u], 1u);
    }
    __syncthreads();
    unsigned c = hb[threadIdx.x];
    if (c) atomicAdd(&p.bins[threadIdx.x], c);
}
__global__ __launch_bounds__(256) void k_rsel(P p, int pass) {
    __shared__ unsigned c[256];
    __shared__ unsigned sfx[257];
    int t = threadIdx.x;
    c[t] = p.bins[t];
    p.bins[t] = 0;                       // reset for next pass
    __syncthreads();
    if (t == 0) {
        unsigned acc = 0;
        sfx[256] = 0;
        for (int b = 255; b >= 0; b--) { acc += c[b]; sfx[b] = acc; }
    }
    __syncthreads();
    unsigned pref = pass ? p.rs[0] : 0u;
    int rem = pass ? (int)p.rs[1] : KK;
    if ((int)sfx[t] >= rem && (int)sfx[t + 1] < rem) {   // unique t
        p.rs[0] = pref | ((unsigned)t << (24 - 8 * pass));
        p.rs[1] = (unsigned)(rem - (int)sfx[t + 1]);
    }
}
__global__ void k_sel(P p) {
    int v = blockIdx.x * blockDim.x + threadIdx.x;
    if (v >= NN) return;
    p.sel[v] = (p.keys[v] > p.rs[0]) ? 1 : 0;
}
__global__ __launch_bounds__(1024) void k_ties(P p) {   // lowest-index ties (matches top_k)
    __shared__ int base;
    __shared__ int wsums[16];
    unsigned pivot = p.rs[0];
    int need = (int)p.rs[1];
    if (threadIdx.x == 0) base = 0;
    __syncthreads();
    for (int st = 0; st < NN; st += 1024) {
        int v = st + (int)threadIdx.x;
        int flag = (v < NN && p.keys[v] == pivot) ? 1 : 0;
        unsigned long long m = __ballot(flag);
        int lane = threadIdx.x & 63, w = threadIdx.x >> 6;
        int pre = __popcll(m & ((1ull << lane) - 1ull));
        if (lane == 0) wsums[w] = __popcll(m);
        __syncthreads();
        int woff = 0;
        for (int i = 0; i < w; i++) woff += wsums[i];
        int rank = base + woff + pre;
        if (flag && rank < need) p.sel[v] = 1;
        __syncthreads();
        if (threadIdx.x == 0) {
            int s = 0;
            for (int i = 0; i < 16; i++) s += wsums[i];
            base += s;
        }
        __syncthreads();
    }
}
__global__ void k_list(P p) {
    int v = blockIdx.x * blockDim.x + threadIdx.x;
    if (v >= NN) return;
    if (p.sel[v]) {
        int i = atomicAdd(p.cnt, 1);
        p.list[i] = v;
        p.slot[v] = i;
        p.tscale[i] = tanhf(p.score[v]);
    } else {
        p.slot[v] = -1;
    }
}
__global__ void k_xk(P p) {
    int gid = blockIdx.x * blockDim.x + threadIdx.x;
    if (gid >= KK * HD) return;
    int i = gid >> 7, c = gid & 127;
    int v = p.list[i];
    p.xk[(size_t)i * HD + c] = p.x[(size_t)v * HD + c] * p.tscale[i];
}

// ---------- layer-1 graph (valid edges only, slot-indexed) ----------
__global__ void k_deg1(P p) {
    int e = blockIdx.x * blockDim.x + threadIdx.x;
    if (e >= EE) return;
    int ds = p.slot[p.src[e]], dd = p.slot[p.dst[e]];
    if (ds >= 0 && dd >= 0) atomicAdd(&p.deg1[dd], 1);
}
__global__ void k_scatter1(P p) {
    int e = blockIdx.x * blockDim.x + threadIdx.x;
    if (e >= EE) return;
    int ds = p.slot[p.src[e]], dd = p.slot[p.dst[e]];
    if (ds >= 0 && dd >= 0) {
        int pos = p.off1[dd] + atomicAdd(&p.cur1[dd], 1);
        p.csr_src[pos] = ds;
    }
}
// per-edge alpha outputs: pure reads, writes atten+strength for ALL edges
__global__ void k_ealpha1(P p) {
    int e = blockIdx.x * blockDim.x + threadIdx.x;
    if (e >= EE) return;
    int ds = p.slot[p.src[e]], dd = p.slot[p.dst[e]];
    float a[4] = {0.f, 0.f, 0.f, 0.f};
    float st = 0.f;
    if (ds >= 0 && dd >= 0) {
        float4 es = *(const float4*)(p.el1 + ds * 4);
        float4 ed = *(const float4*)(p.er1 + dd * 4);
        float l[4] = {lrelu(es.x + ed.x), lrelu(es.y + ed.y), lrelu(es.z + ed.z), lrelu(es.w + ed.w)};
#pragma unroll
        for (int h = 0; h < 4; h++) {
            float m = p.m1f[dd * 4 + h];
            float ex = expf(l[h] - m);
            a[h] = ex / fmaxf(p.s1f[dd * 4 + h], 1e-16f);
        }
        st = p.strength[e];
    }
    float* o = p.out + ATT_OFF + (size_t)e * 4;
    o[0] = a[0]; o[1] = a[1]; o[2] = a[2]; o[3] = a[3];
    p.out[STR_OFF + e] = st;
}

// ---------- readout ----------
__global__ void k_gmax(P p) {
    __shared__ float red[256];
    int t = threadIdx.x;
    float m = -3.4e38f;
    for (int i = blockIdx.x * 256 + t; i < KK; i += gridDim.x * 256) m = fmaxf(m, p.g[i]);
    red[t] = m;
    __syncthreads();
    for (int o = 128; o > 0; o >>= 1) { if (t < o) red[t] = fmaxf(red[t], red[t + o]); __syncthreads(); }
    if (t == 0) atomicMax(p.gmaxk, fkey(red[0]));   // memset-0 identity ok
}
// grid-strided + pre-aggregated: was 3125 blocks x 33 hot fp64 atomics (R2 lesson)
#define WSUM_BLOCKS 104
__global__ __launch_bounds__(256) void k_wsum(P p) {
    __shared__ double vred[256];
    __shared__ double zred[8];
    int t = threadIdx.x, il = t >> 5, d = t & 31;
    float gm = unfkey(*p.gmaxk);
    double accv = 0.0, accw = 0.0;
    for (int i = blockIdx.x * 8 + il; i < KK; i += WSUM_BLOCKS * 8) {
        float w = expf(p.g[i] - gm);
        accv += (double)(w * p.res[(size_t)i * 32 + d]);
        if (d == 0) accw += (double)w;
    }
    vred[t] = accv;
    if (d == 0) zred[il] = accw;
    __syncthreads();
    if (il == 0) {
        double s = 0;
#pragma unroll
        for (int k2 = 0; k2 < 8; k2++) s += vred[k2 * 32 + d];
        atomicAdd(&p.racc[d], s);
    }
    if (t == 32) {
        double z2 = 0;
#pragma unroll
        for (int k2 = 0; k2 < 8; k2++) z2 += zred[k2];
        atomicAdd(p.Zacc, z2);
    }
}
__global__ void k_final(P p) {
    __shared__ float rb[32];
    int t = threadIdx.x;
    double Z = *p.Zacc;
    if (t < 32) {
        float r = (float)(p.racc[t] / Z);
        p.out[t] = r;
        rb[t] = r;
    }
    __syncthreads();
    if (t < 2) {
        float s = 0.f;
        for (int d = 0; d < 32; d++) s += rb[d] * p.cW[d * 2 + t];
        p.out[32 + t] = s + p.cb[t];
    }
}

// ---------- host ----------
extern "C" void kernel_launch(void* const* d_in, const int* in_sizes, int n_in,
                              void* d_out, int out_size, void* d_ws, size_t ws_size,
                              hipStream_t stream) {
    (void)in_sizes; (void)n_in; (void)out_size; (void)ws_size;
    P p;
    p.feature  = (const float*)d_in[0];
    p.strength = (const float*)d_in[1];
    p.W0  = (const float*)d_in[2];  p.b0  = (const float*)d_in[3];
    p.al0 = (const float*)d_in[4];  p.ar0 = (const float*)d_in[5];
    p.Wc0 = (const float*)d_in[6];  p.bc0 = (const float*)d_in[7];
    p.W1  = (const float*)d_in[8];  p.b1  = (const float*)d_in[9];
    p.al1 = (const float*)d_in[10]; p.ar1 = (const float*)d_in[11];
    p.gW  = (const float*)d_in[12]; p.gb  = (const float*)d_in[13];
    p.cW  = (const float*)d_in[14]; p.cb  = (const float*)d_in[15];
    p.src = (const int*)d_in[16];   p.dst = (const int*)d_in[17];
    p.out = (float*)d_out;

    char* ws = (char*)d_ws;
    size_t off = 0;
    auto alloc = [&](size_t bytes) -> void* {
        void* r = ws + off;
        off = (off + bytes + 255) & ~(size_t)255;
        return r;
    };
    // ---- zeroed region (must stay first/contiguous) ----
    p.Zacc  = (double*)alloc(8);
    p.racc  = (double*)alloc(32 * 8);
    p.deg_i = (int*)alloc((size_t)NN * 4);
    p.deg_o = (int*)alloc((size_t)NN * 4);
    p.cur0  = (int*)alloc((size_t)NN * 4);
    p.deg1  = (int*)alloc((size_t)KK * 4);
    p.cur1  = (int*)alloc((size_t)KK * 4);
    p.bins  = (unsigned*)alloc(256 * 4);
    p.cnt   = (int*)alloc(4);
    p.gmaxk = (unsigned*)alloc(4);
    p.rs    = (unsigned*)alloc(8);
    size_t zbytes = off;
    // ---- big buffers (lifetime overlays) ----
    p.z0 = (float*)alloc((size_t)NN * HD * 4);
    p.x  = (float*)alloc((size_t)NN * HD * 4);   // after k_xk, reused as z1
    p.z1 = p.x;
    p.xk = (float*)alloc((size_t)KK * HD * 4);
    p.csr_src = (int*)alloc((size_t)EE * 4);
    p.el0 = (float*)alloc((size_t)NN * 4 * 4);
    p.er0 = (float*)alloc((size_t)NN * 4 * 4);
    p.off0 = (int*)alloc((size_t)(NN + 1) * 4);
    p.off1 = (int*)alloc((size_t)(KK + 1) * 4);
    p.hc    = (float*)alloc((size_t)NN * 4);
    p.score = (float*)alloc((size_t)NN * 4);
    p.keys  = (unsigned*)alloc((size_t)NN * 4);
    p.sel   = (int*)alloc((size_t)NN * 4);
    p.slot  = (int*)alloc((size_t)NN * 4);
    p.list  = (int*)alloc((size_t)KK * 4);
    p.tscale = (float*)alloc((size_t)KK * 4);
    p.el1 = (float*)alloc((size_t)KK * 4 * 4);
    p.er1 = (float*)alloc((size_t)KK * 4 * 4);
    p.m1f = (float*)alloc((size_t)KK * 4 * 4);
    p.s1f = (float*)alloc((size_t)KK * 4 * 4);
    p.res = (float*)alloc((size_t)KK * DD * 4);
    p.g   = (float*)alloc((size_t)KK * 4);

    const int GB_E  = (EE + 255) / 256;        // 3125
    const int GB_N  = (NN + 255) / 256;        // 196
    const int GB_N4 = (NN * 4 + 255) / 256;    // 782
    const int GB_K4 = (KK * 4 + 255) / 256;    // 391

    hipMemsetAsync(d_ws, 0, zbytes, stream);

    // ---- GAT layer 0 ----
    k_gemm<<<dim3(HD / BN, (NN + BM - 1) / BM), 256, 0, stream>>>(p.feature, p.W0, p.z0, NN, HD, FIN);
    k_elr<<<GB_N4, 256, 0, stream>>>(p.z0, p.al0, p.ar0, p.el0, p.er0, NN);
    k_deg<<<GB_E, 256, 0, stream>>>(p);
    k_scan<<<1, 1024, 0, stream>>>(p.deg_i, p.off0, NN);
    k_scatter0<<<GB_E, 256, 0, stream>>>(p);
    k_fgat<1><<<NN, 128, 0, stream>>>(p.off0, p.csr_src, p.el0, p.er0, p.z0, p.b0,
                                      p.x, nullptr, nullptr,
                                      p.Wc0, p.deg_o, p.hc,
                                      nullptr, nullptr, nullptr, nullptr);

    // ---- SAGPool ----
    k_score<<<GB_N, 256, 0, stream>>>(p);
    for (int pass = 0; pass < 4; pass++) {
        k_hist<<<HIST_BLOCKS, 256, 0, stream>>>(p, pass);
        k_rsel<<<1, 256, 0, stream>>>(p, pass);
    }
    k_sel<<<GB_N, 256, 0, stream>>>(p);
    k_ties<<<1, 1024, 0, stream>>>(p);
    k_list<<<GB_N, 256, 0, stream>>>(p);
    k_xk<<<(KK * HD + 255) / 256, 256, 0, stream>>>(p);

    // ---- GAT layer 1 ----
    k_gemm<<<dim3(HD / BN, (KK + BM - 1) / BM), 256, 0, stream>>>(p.xk, p.W1, p.z1, KK, HD, HD);
    k_elr<<<GB_K4, 256, 0, stream>>>(p.z1, p.al1, p.ar1, p.el1, p.er1, KK);
    k_deg1<<<GB_E, 256, 0, stream>>>(p);
    k_scan<<<1, 1024, 0, stream>>>(p.deg1, p.off1, KK);
    k_scatter1<<<GB_E, 256, 0, stream>>>(p);
    k_fgat<2><<<KK, 128, 0, stream>>>(p.off1, p.csr_src, p.el1, p.er1, p.z1, p.b1,
                                      nullptr, p.m1f, p.s1f,
                                      nullptr, nullptr, nullptr,
                                      p.gW, p.gb, p.res, p.g);
    k_ealpha1<<<GB_E, 256, 0, stream>>>(p);

    // ---- readout ----
    k_gmax<<<98, 256, 0, stream>>>(p);
    k_wsum<<<WSUM_BLOCKS, 256, 0, stream>>>(p);
    k_final<<<1, 64, 0, stream>>>(p);
}

// Round 5
// 723.835 us; speedup vs baseline: 2.1889x; 1.0207x over previous
//
#include <hip/hip_runtime.h>
#include <stdint.h>

#define NN 50000
#define EE 800000
#define FIN 256
#define HD 128
#define DD 32
#define KK 25000
#define SLOPEF 0.4f
#define NEGF (-1e9f)
#define ATT_OFF 34
#define STR_OFF (34 + EE * 4)
#define CAP 128            // LDS-cached edges per node (deg ~Poisson(16); recompute fallback kept)

// ---------- helpers ----------
__device__ __forceinline__ unsigned fkey(float x) {
    unsigned u = __float_as_uint(x);
    return (u & 0x80000000u) ? ~u : (u | 0x80000000u);   // monotone float->uint
}
__device__ __forceinline__ float unfkey(unsigned k) {
    unsigned u = (k & 0x80000000u) ? (k ^ 0x80000000u) : ~k;
    return __uint_as_float(u);
}
__device__ __forceinline__ float lrelu(float v) { return v > 0.f ? v : SLOPEF * v; }

// ---------- pointer bundle ----------
struct P {
    // inputs
    const float *feature, *strength, *W0, *b0, *al0, *ar0, *Wc0, *bc0;
    const float *W1, *b1, *al1, *ar1, *gW, *gb, *cW, *cb;
    const int *src, *dst;
    // zeroed scratch
    double *Zacc, *racc;
    int *deg_i, *deg_o, *cur0, *deg1, *cur1, *cnt;
    unsigned *bins, *gmaxk, *rs;      // rs[0]=prefix/pivot, rs[1]=remaining
    // other scratch
    unsigned *keys;
    int *csr_src, *off0, *off1, *sel, *slot, *list;
    float *z0, *x, *el0, *er0, *hc, *score, *xk, *z1;
    float *el1, *er1, *m1f, *s1f, *res, *g, *tscale;
    float *out;                        // d_out (float32)
};

// ---------- fp32 tiled GEMM: C[M,Nd] = A[M,Kd] @ B[Kd,Nd] ----------
// 128x64 tile, 8x4 acc/thread: 32 FMA per 12 LDS-floats (was 16:8 at 64x64).
#define BM 128
#define BN 64
#define BK 16
__global__ __launch_bounds__(256) void k_gemm(const float* __restrict__ A,
                                              const float* __restrict__ B,
                                              float* __restrict__ C,
                                              int M, int Nd, int Kd) {
    __shared__ float As[BK][BM + 4];   // +4 pad keeps b128 alignment, 2-way max
    __shared__ float Bs[BK][BN];
    int bm = blockIdx.y * BM, bn = blockIdx.x * BN;
    int tid = threadIdx.x;
    int tr = tid >> 4, tc = tid & 15;  // 16x16 threads, each 8x4
    float acc[8][4] = {};
    for (int k0 = 0; k0 < Kd; k0 += BK) {
        {   // A tile: 128 rows x 16 k; 2 threads/row, 8 cols each
            int row = tid >> 1, col = (tid & 1) << 3;
            int gr = bm + row;
            float4 v0 = {0.f, 0.f, 0.f, 0.f}, v1 = {0.f, 0.f, 0.f, 0.f};
            if (gr < M) {
                v0 = *(const float4*)(A + (size_t)gr * Kd + k0 + col);
                v1 = *(const float4*)(A + (size_t)gr * Kd + k0 + col + 4);
            }
            As[col + 0][row] = v0.x; As[col + 1][row] = v0.y;
            As[col + 2][row] = v0.z; As[col + 3][row] = v0.w;
            As[col + 4][row] = v1.x; As[col + 5][row] = v1.y;
            As[col + 6][row] = v1.z; As[col + 7][row] = v1.w;
        }
        {   // B tile: 16 k x 64 cols
            int kr = tid >> 4, col = (tid & 15) << 2;
            float4 v = *(const float4*)(B + (size_t)(k0 + kr) * Nd + bn + col);
            *(float4*)&Bs[kr][col] = v;
        }
        __syncthreads();
#pragma unroll
        for (int kk = 0; kk < BK; kk++) {
            float a[8], b[4];
#pragma unroll
            for (int i = 0; i < 8; i++) a[i] = As[kk][tr * 8 + i];
#pragma unroll
            for (int j = 0; j < 4; j++) b[j] = Bs[kk][tc * 4 + j];
#pragma unroll
            for (int i = 0; i < 8; i++)
#pragma unroll
                for (int j = 0; j < 4; j++) acc[i][j] = fmaf(a[i], b[j], acc[i][j]);
        }
        __syncthreads();
    }
#pragma unroll
    for (int i = 0; i < 8; i++) {
        int gr = bm + tr * 8 + i;
        if (gr < M) {
            float4 v = {acc[i][0], acc[i][1], acc[i][2], acc[i][3]};
            *(float4*)(C + (size_t)gr * Nd + bn + tc * 4) = v;
        }
    }
}

// ---------- per-(node,head) attn logits el/er ----------
__global__ void k_elr(const float* __restrict__ z, const float* __restrict__ al,
                      const float* __restrict__ ar, float* __restrict__ el,
                      float* __restrict__ er, int n) {
    int i = blockIdx.x * blockDim.x + threadIdx.x;
    if (i >= n * 4) return;
    int v = i >> 2, h = i & 3;
    const float* zr = z + (size_t)v * HD + h * DD;
    const float* a = al + h * DD;
    const float* b = ar + h * DD;
    float sa = 0.f, sb = 0.f;
#pragma unroll
    for (int d = 0; d < DD; d++) { float zv = zr[d]; sa += zv * a[d]; sb += zv * b[d]; }
    el[i] = sa; er[i] = sb;
}

// ---------- degrees ----------
__global__ void k_deg(P p) {
    int e = blockIdx.x * blockDim.x + threadIdx.x;
    if (e >= EE) return;
    atomicAdd(&p.deg_i[p.dst[e]], 1);
    atomicAdd(&p.deg_o[p.src[e]], 1);
}

// ---------- exclusive scan (single block 1024, wave shfl-scan) ----------
__global__ __launch_bounds__(1024) void k_scan(const int* __restrict__ deg, int* __restrict__ off, int n) {
    __shared__ int ws[16];
    __shared__ int woff[17];
    int t = threadIdx.x;
    int per = (n + 1023) / 1024;
    int s0 = t * per; if (s0 > n) s0 = n;
    int e0 = s0 + per; if (e0 > n) e0 = n;
    int s = 0;
    for (int i = s0; i < e0; i++) s += deg[i];
    int lane = t & 63, w = t >> 6;
    int val = s;
    for (int o = 1; o < 64; o <<= 1) { int u = __shfl_up(val, o); if (lane >= o) val += u; }
    if (lane == 63) ws[w] = val;
    __syncthreads();
    if (t == 0) { int a = 0; for (int i = 0; i < 16; i++) { woff[i] = a; a += ws[i]; } woff[16] = a; }
    __syncthreads();
    if (t == 0) off[n] = woff[16];
    int acc = woff[w] + val - s;   // exclusive prefix
    for (int i = s0; i < e0; i++) { off[i] = acc; acc += deg[i]; }
}

// ---------- CSR scatter (src-ids only) ----------
__global__ void k_scatter0(P p) {
    int e = blockIdx.x * blockDim.x + threadIdx.x;
    if (e >= EE) return;
    int d = p.dst[e];
    int pos = p.off0[d] + atomicAdd(&p.cur0[d], 1);
    p.csr_src[pos] = p.src[e];
}

// ---------- FUSED GAT aggregate: softmax (max/sum) + weighted z-gather ----------
// One block (128 thr) per dst node.
// Phases 1-2 head-split across BOTH waves (wave w: heads 2w,2w+1; R4 had wave 1
// idle). Phase 3 channel-parallel: fp32 CSR-order serial accumulate (deterministic,
// fp32-noise level — jax-fp32 ref passes so selection is robust to this), row base
// scalarized via readfirstlane (s is block-uniform -> SGPR-base loads).
template <int EPI>
__global__ __launch_bounds__(128) void k_fgat(
    const int* __restrict__ off, const int* __restrict__ csrs,
    const float* __restrict__ el, const float* __restrict__ er,
    const float* __restrict__ z, const float* __restrict__ bias,
    float* __restrict__ xout, float* __restrict__ mf, float* __restrict__ sf,
    const float* __restrict__ Wc, const int* __restrict__ dego, float* __restrict__ hc,
    const float* __restrict__ gW, const float* __restrict__ gb,
    float* __restrict__ res, float* __restrict__ g) {
    int v = blockIdx.x;
    int b = off[v], e = off[v + 1], deg = e - b;
    __shared__ float sexp[4 * CAP];
    __shared__ int ssrc[CAP];
    __shared__ float smh[4], ssh[4];
    __shared__ float lred[128];
    int tid = threadIdx.x;
    int wv = tid >> 6, lane = tid & 63;
    int hbase = wv * 2;
    float4 er4 = *(const float4*)(er + (size_t)v * 4);
    float erA = wv ? er4.z : er4.x;
    float erB = wv ? er4.w : er4.y;
    // phase 1: max for this wave's 2 heads
    float mA = NEGF, mB = NEGF;
    for (int li = lane; li < deg; li += 64) {
        int s = csrs[b + li];
        if (wv == 0 && li < CAP) ssrc[li] = s;
        float2 e2 = *(const float2*)(el + (size_t)s * 4 + hbase);
        mA = fmaxf(mA, lrelu(e2.x + erA));
        mB = fmaxf(mB, lrelu(e2.y + erB));
    }
    for (int o = 32; o; o >>= 1) {
        mA = fmaxf(mA, __shfl_down(mA, o));
        mB = fmaxf(mB, __shfl_down(mB, o));
    }
    if (lane == 0) { smh[hbase] = mA; smh[hbase + 1] = mB; }
    __syncthreads();
    // phase 2: exp + fp64-reduced sum
    mA = smh[hbase]; mB = smh[hbase + 1];
    double sA = 0.0, sB = 0.0;
    for (int li = lane; li < deg; li += 64) {
        int s = (li < CAP) ? ssrc[li] : csrs[b + li];
        float2 e2 = *(const float2*)(el + (size_t)s * 4 + hbase);
        float xA = expf(lrelu(e2.x + erA) - mA);
        float xB = expf(lrelu(e2.y + erB) - mB);
        if (li < CAP) { sexp[hbase * CAP + li] = xA; sexp[(hbase + 1) * CAP + li] = xB; }
        sA += (double)xA; sB += (double)xB;
    }
    for (int o = 32; o; o >>= 1) { sA += __shfl_down(sA, o); sB += __shfl_down(sB, o); }
    if (lane == 0) { ssh[hbase] = (float)sA; ssh[hbase + 1] = (float)sB; }
    __syncthreads();
    if (mf && tid < 4) { mf[v * 4 + tid] = smh[tid]; sf[v * 4 + tid] = ssh[tid]; }
    // phase 3: channel-parallel weighted gather (fp32, CSR order)
    int c = tid, h = c >> 5;
    const float* sexph = sexp + h * CAP;
    float acc = 0.f;
    if (deg <= CAP) {
        int li = 0;
        for (; li + 2 <= deg; li += 2) {
            int s0 = __builtin_amdgcn_readfirstlane(ssrc[li]);
            int s1 = __builtin_amdgcn_readfirstlane(ssrc[li + 1]);
            float w0 = sexph[li], w1 = sexph[li + 1];
            float z0v = z[(size_t)s0 * HD + c];
            float z1v = z[(size_t)s1 * HD + c];
            acc = fmaf(w0, z0v, acc);
            acc = fmaf(w1, z1v, acc);
        }
        if (li < deg) {
            int s0 = __builtin_amdgcn_readfirstlane(ssrc[li]);
            acc = fmaf(sexph[li], z[(size_t)s0 * HD + c], acc);
        }
    } else {
        float mmh = smh[h];
        float erh = (h == 0) ? er4.x : (h == 1) ? er4.y : (h == 2) ? er4.z : er4.w;
        for (int li = 0; li < deg; li++) {
            int s = csrs[b + li];
            float w = expf(lrelu(el[(size_t)s * 4 + h] + erh) - mmh);
            acc = fmaf(w, z[(size_t)s * HD + c], acc);
        }
    }
    float xc = acc / fmaxf(ssh[h], 1e-16f) + bias[c];
    if (EPI == 1) {
        xout[(size_t)v * HD + c] = xc;
        float pc = xc * Wc[c];
        for (int o = 32; o; o >>= 1) pc += __shfl_down(pc, o);
        if ((tid & 63) == 0) lred[tid >> 6] = pc;
        __syncthreads();
        if (tid == 0) hc[v] = (lred[0] + lred[1]) / sqrtf(fmaxf((float)dego[v], 1.f));
    }
    if (EPI == 2) {
        lred[c] = xc;
        __syncthreads();
        if (c < 32) {
            float r = 0.25f * (lred[c] + lred[c + 32] + lred[c + 64] + lred[c + 96]);
            res[(size_t)v * 32 + c] = r;
            float pg = r * gW[c];
            for (int o = 16; o; o >>= 1) pg += __shfl_down(pg, o);
            if (c == 0) g[v] = pg + gb[0];
        }
    }
}

// ---------- SAGPool score ----------
__global__ void k_score(P p) {
    int v = blockIdx.x * blockDim.x + threadIdx.x;
    if (v >= NN) return;
    int b = p.off0[v], en = p.off0[v + 1];
    float acc = 0.f;
    for (int i = b; i < en; i++) acc += p.hc[p.csr_src[i]];
    float dg = fmaxf((float)p.deg_i[v], 1.f);
    float sc = acc / sqrtf(dg) + p.bc0[0];
    p.score[v] = sc;
    p.keys[v] = fkey(sc);
}

// ---------- radix select (K-th largest key) ----------
#define HIST_BLOCKS 100
__global__ __launch_bounds__(256) void k_hist(P p, int pass) {
    __shared__ unsigned hb[256];
    hb[threadIdx.x] = 0;
    __syncthreads();
    unsigned maskhi = pass ? (0xFFFFFFFFu << (32 - 8 * pass)) : 0u;
    unsigned pref = pass ? (p.rs[0] & maskhi) : 0u;
    int shift = 24 - 8 * pass;
    for (int v = blockIdx.x * 256 + threadIdx.x; v < NN; v += HIST_BLOCKS * 256) {
        unsigned key = p.keys[v];
        if ((key & maskhi) == pref)
            atomicAdd(&hb[(key >> shift) & 255u], 1u);
    }
    __syncthreads();
    unsigned c = hb[threadIdx.x];
    if (c) atomicAdd(&p.bins[threadIdx.x], c);
}
__global__ __launch_bounds__(256) void k_rsel(P p, int pass) {
    __shared__ unsigned c[256];
    __shared__ unsigned sfx[257];
    int t = threadIdx.x;
    c[t] = p.bins[t];
    p.bins[t] = 0;                       // reset for next pass
    __syncthreads();
    if (t == 0) {
        unsigned acc = 0;
        sfx[256] = 0;
        for (int b = 255; b >= 0; b--) { acc += c[b]; sfx[b] = acc; }
    }
    __syncthreads();
    unsigned pref = pass ? p.rs[0] : 0u;
    int rem = pass ? (int)p.rs[1] : KK;
    if ((int)sfx[t] >= rem && (int)sfx[t + 1] < rem) {   // unique t
        p.rs[0] = pref | ((unsigned)t << (24 - 8 * pass));
        p.rs[1] = (unsigned)(rem - (int)sfx[t + 1]);
    }
}
__global__ void k_sel(P p) {
    int v = blockIdx.x * blockDim.x + threadIdx.x;
    if (v >= NN) return;
    p.sel[v] = (p.keys[v] > p.rs[0]) ? 1 : 0;
}
__global__ __launch_bounds__(1024) void k_ties(P p) {   // lowest-index ties (matches top_k)
    __shared__ int base;
    __shared__ int wsums[16];
    unsigned pivot = p.rs[0];
    int need = (int)p.rs[1];
    if (threadIdx.x == 0) base = 0;
    __syncthreads();
    for (int st = 0; st < NN; st += 1024) {
        int v = st + (int)threadIdx.x;
        int flag = (v < NN && p.keys[v] == pivot) ? 1 : 0;
        unsigned long long m = __ballot(flag);
        int lane = threadIdx.x & 63, w = threadIdx.x >> 6;
        int pre = __popcll(m & ((1ull << lane) - 1ull));
        if (lane == 0) wsums[w] = __popcll(m);
        __syncthreads();
        int woff = 0;
        for (int i = 0; i < w; i++) woff += wsums[i];
        int rank = base + woff + pre;
        if (flag && rank < need) p.sel[v] = 1;
        __syncthreads();
        if (threadIdx.x == 0) {
            int s = 0;
            for (int i = 0; i < 16; i++) s += wsums[i];
            base += s;
        }
        __syncthreads();
    }
}
__global__ void k_list(P p) {
    int v = blockIdx.x * blockDim.x + threadIdx.x;
    if (v >= NN) return;
    if (p.sel[v]) {
        int i = atomicAdd(p.cnt, 1);
        p.list[i] = v;
        p.slot[v] = i;
        p.tscale[i] = tanhf(p.score[v]);
    } else {
        p.slot[v] = -1;
    }
}
__global__ void k_xk(P p) {
    int gid = blockIdx.x * blockDim.x + threadIdx.x;
    if (gid >= KK * HD) return;
    int i = gid >> 7, c = gid & 127;
    int v = p.list[i];
    p.xk[(size_t)i * HD + c] = p.x[(size_t)v * HD + c] * p.tscale[i];
}

// ---------- layer-1 graph (valid edges only, slot-indexed) ----------
__global__ void k_deg1(P p) {
    int e = blockIdx.x * blockDim.x + threadIdx.x;
    if (e >= EE) return;
    int ds = p.slot[p.src[e]], dd = p.slot[p.dst[e]];
    if (ds >= 0 && dd >= 0) atomicAdd(&p.deg1[dd], 1);
}
__global__ void k_scatter1(P p) {
    int e = blockIdx.x * blockDim.x + threadIdx.x;
    if (e >= EE) return;
    int ds = p.slot[p.src[e]], dd = p.slot[p.dst[e]];
    if (ds >= 0 && dd >= 0) {
        int pos = p.off1[dd] + atomicAdd(&p.cur1[dd], 1);
        p.csr_src[pos] = ds;
    }
}
// per-edge alpha outputs: pure reads, writes atten+strength for ALL edges
__global__ void k_ealpha1(P p) {
    int e = blockIdx.x * blockDim.x + threadIdx.x;
    if (e >= EE) return;
    int ds = p.slot[p.src[e]], dd = p.slot[p.dst[e]];
    float a[4] = {0.f, 0.f, 0.f, 0.f};
    float st = 0.f;
    if (ds >= 0 && dd >= 0) {
        float4 es = *(const float4*)(p.el1 + ds * 4);
        float4 ed = *(const float4*)(p.er1 + dd * 4);
        float l[4] = {lrelu(es.x + ed.x), lrelu(es.y + ed.y), lrelu(es.z + ed.z), lrelu(es.w + ed.w)};
#pragma unroll
        for (int h = 0; h < 4; h++) {
            float m = p.m1f[dd * 4 + h];
            float ex = expf(l[h] - m);
            a[h] = ex / fmaxf(p.s1f[dd * 4 + h], 1e-16f);
        }
        st = p.strength[e];
    }
    float* o = p.out + ATT_OFF + (size_t)e * 4;
    o[0] = a[0]; o[1] = a[1]; o[2] = a[2]; o[3] = a[3];
    p.out[STR_OFF + e] = st;
}

// ---------- readout ----------
__global__ void k_gmax(P p) {
    __shared__ float red[256];
    int t = threadIdx.x;
    float m = -3.4e38f;
    for (int i = blockIdx.x * 256 + t; i < KK; i += gridDim.x * 256) m = fmaxf(m, p.g[i]);
    red[t] = m;
    __syncthreads();
    for (int o = 128; o > 0; o >>= 1) { if (t < o) red[t] = fmaxf(red[t], red[t + o]); __syncthreads(); }
    if (t == 0) atomicMax(p.gmaxk, fkey(red[0]));   // memset-0 identity ok
}
// grid-strided + pre-aggregated (R2 lesson: no hot fp64 atomics)
#define WSUM_BLOCKS 104
__global__ __launch_bounds__(256) void k_wsum(P p) {
    __shared__ double vred[256];
    __shared__ double zred[8];
    int t = threadIdx.x, il = t >> 5, d = t & 31;
    float gm = unfkey(*p.gmaxk);
    double accv = 0.0, accw = 0.0;
    for (int i = blockIdx.x * 8 + il; i < KK; i += WSUM_BLOCKS * 8) {
        float w = expf(p.g[i] - gm);
        accv += (double)(w * p.res[(size_t)i * 32 + d]);
        if (d == 0) accw += (double)w;
    }
    vred[t] = accv;
    if (d == 0) zred[il] = accw;
    __syncthreads();
    if (il == 0) {
        double s = 0;
#pragma unroll
        for (int k2 = 0; k2 < 8; k2++) s += vred[k2 * 32 + d];
        atomicAdd(&p.racc[d], s);
    }
    if (t == 32) {
        double z2 = 0;
#pragma unroll
        for (int k2 = 0; k2 < 8; k2++) z2 += zred[k2];
        atomicAdd(p.Zacc, z2);
    }
}
__global__ void k_final(P p) {
    __shared__ float rb[32];
    int t = threadIdx.x;
    double Z = *p.Zacc;
    if (t < 32) {
        float r = (float)(p.racc[t] / Z);
        p.out[t] = r;
        rb[t] = r;
    }
    __syncthreads();
    if (t < 2) {
        float s = 0.f;
        for (int d = 0; d < 32; d++) s += rb[d] * p.cW[d * 2 + t];
        p.out[32 + t] = s + p.cb[t];
    }
}

// ---------- host ----------
extern "C" void kernel_launch(void* const* d_in, const int* in_sizes, int n_in,
                              void* d_out, int out_size, void* d_ws, size_t ws_size,
                              hipStream_t stream) {
    (void)in_sizes; (void)n_in; (void)out_size; (void)ws_size;
    P p;
    p.feature  = (const float*)d_in[0];
    p.strength = (const float*)d_in[1];
    p.W0  = (const float*)d_in[2];  p.b0  = (const float*)d_in[3];
    p.al0 = (const float*)d_in[4];  p.ar0 = (const float*)d_in[5];
    p.Wc0 = (const float*)d_in[6];  p.bc0 = (const float*)d_in[7];
    p.W1  = (const float*)d_in[8];  p.b1  = (const float*)d_in[9];
    p.al1 = (const float*)d_in[10]; p.ar1 = (const float*)d_in[11];
    p.gW  = (const float*)d_in[12]; p.gb  = (const float*)d_in[13];
    p.cW  = (const float*)d_in[14]; p.cb  = (const float*)d_in[15];
    p.src = (const int*)d_in[16];   p.dst = (const int*)d_in[17];
    p.out = (float*)d_out;

    char* ws = (char*)d_ws;
    size_t off = 0;
    auto alloc = [&](size_t bytes) -> void* {
        void* r = ws + off;
        off = (off + bytes + 255) & ~(size_t)255;
        return r;
    };
    // ---- zeroed region (must stay first/contiguous) ----
    p.Zacc  = (double*)alloc(8);
    p.racc  = (double*)alloc(32 * 8);
    p.deg_i = (int*)alloc((size_t)NN * 4);
    p.deg_o = (int*)alloc((size_t)NN * 4);
    p.cur0  = (int*)alloc((size_t)NN * 4);
    p.deg1  = (int*)alloc((size_t)KK * 4);
    p.cur1  = (int*)alloc((size_t)KK * 4);
    p.bins  = (unsigned*)alloc(256 * 4);
    p.cnt   = (int*)alloc(4);
    p.gmaxk = (unsigned*)alloc(4);
    p.rs    = (unsigned*)alloc(8);
    size_t zbytes = off;
    // ---- big buffers (lifetime overlays) ----
    p.z0 = (float*)alloc((size_t)NN * HD * 4);
    p.x  = (float*)alloc((size_t)NN * HD * 4);   // after k_xk, reused as z1
    p.z1 = p.x;
    p.xk = (float*)alloc((size_t)KK * HD * 4);
    p.csr_src = (int*)alloc((size_t)EE * 4);
    p.el0 = (float*)alloc((size_t)NN * 4 * 4);
    p.er0 = (float*)alloc((size_t)NN * 4 * 4);
    p.off0 = (int*)alloc((size_t)(NN + 1) * 4);
    p.off1 = (int*)alloc((size_t)(KK + 1) * 4);
    p.hc    = (float*)alloc((size_t)NN * 4);
    p.score = (float*)alloc((size_t)NN * 4);
    p.keys  = (unsigned*)alloc((size_t)NN * 4);
    p.sel   = (int*)alloc((size_t)NN * 4);
    p.slot  = (int*)alloc((size_t)NN * 4);
    p.list  = (int*)alloc((size_t)KK * 4);
    p.tscale = (float*)alloc((size_t)KK * 4);
    p.el1 = (float*)alloc((size_t)KK * 4 * 4);
    p.er1 = (float*)alloc((size_t)KK * 4 * 4);
    p.m1f = (float*)alloc((size_t)KK * 4 * 4);
    p.s1f = (float*)alloc((size_t)KK * 4 * 4);
    p.res = (float*)alloc((size_t)KK * DD * 4);
    p.g   = (float*)alloc((size_t)KK * 4);

    const int GB_E  = (EE + 255) / 256;        // 3125
    const int GB_N  = (NN + 255) / 256;        // 196
    const int GB_N4 = (NN * 4 + 255) / 256;    // 782
    const int GB_K4 = (KK * 4 + 255) / 256;    // 391

    hipMemsetAsync(d_ws, 0, zbytes, stream);

    // ---- GAT layer 0 ----
    k_gemm<<<dim3(HD / BN, (NN + BM - 1) / BM), 256, 0, stream>>>(p.feature, p.W0, p.z0, NN, HD, FIN);
    k_elr<<<GB_N4, 256, 0, stream>>>(p.z0, p.al0, p.ar0, p.el0, p.er0, NN);
    k_deg<<<GB_E, 256, 0, stream>>>(p);
    k_scan<<<1, 1024, 0, stream>>>(p.deg_i, p.off0, NN);
    k_scatter0<<<GB_E, 256, 0, stream>>>(p);
    k_fgat<1><<<NN, 128, 0, stream>>>(p.off0, p.csr_src, p.el0, p.er0, p.z0, p.b0,
                                      p.x, nullptr, nullptr,
                                      p.Wc0, p.deg_o, p.hc,
                                      nullptr, nullptr, nullptr, nullptr);

    // ---- SAGPool ----
    k_score<<<GB_N, 256, 0, stream>>>(p);
    for (int pass = 0; pass < 4; pass++) {
        k_hist<<<HIST_BLOCKS, 256, 0, stream>>>(p, pass);
        k_rsel<<<1, 256, 0, stream>>>(p, pass);
    }
    k_sel<<<GB_N, 256, 0, stream>>>(p);
    k_ties<<<1, 1024, 0, stream>>>(p);
    k_list<<<GB_N, 256, 0, stream>>>(p);
    k_xk<<<(KK * HD + 255) / 256, 256, 0, stream>>>(p);

    // ---- GAT layer 1 ----
    k_gemm<<<dim3(HD / BN, (KK + BM - 1) / BM), 256, 0, stream>>>(p.xk, p.W1, p.z1, KK, HD, HD);
    k_elr<<<GB_K4, 256, 0, stream>>>(p.z1, p.al1, p.ar1, p.el1, p.er1, KK);
    k_deg1<<<GB_E, 256, 0, stream>>>(p);
    k_scan<<<1, 1024, 0, stream>>>(p.deg1, p.off1, KK);
    k_scatter1<<<GB_E, 256, 0, stream>>>(p);
    k_fgat<2><<<KK, 128, 0, stream>>>(p.off1, p.csr_src, p.el1, p.er1, p.z1, p.b1,
                                      nullptr, p.m1f, p.s1f,
                                      nullptr, nullptr, nullptr,
                                      p.gW, p.gb, p.res, p.g);
    k_ealpha1<<<GB_E, 256, 0, stream>>>(p);

    // ---- readout ----
    k_gmax<<<98, 256, 0, stream>>>(p);
    k_wsum<<<WSUM_BLOCKS, 256, 0, stream>>>(p);
    k_final<<<1, 64, 0, stream>>>(p);
}